// Round 4
// baseline (441.123 us; speedup 1.0000x reference)
//
#include <hip/hip_runtime.h>

// Problem constants
#define Bz 4
#define Sz 2048
#define Dz 1024
#define Hz 16
#define HDz 64
#define Rz 512
#define Mz (Bz * Sz)  // 8192 total rows

typedef unsigned short u16;
typedef __bf16 bf16x8 __attribute__((ext_vector_type(8)));
typedef __bf16 bf16x4 __attribute__((ext_vector_type(4)));
typedef float f32x4 __attribute__((ext_vector_type(4)));
typedef u16 u16x8 __attribute__((ext_vector_type(8)));
typedef u16 u16x4 __attribute__((ext_vector_type(4)));

__device__ __forceinline__ u16 f2bf(float f) {
  unsigned u = __builtin_bit_cast(unsigned, f);
  u += 0x7fffu + ((u >> 16) & 1u);  // RNE
  return (u16)(u >> 16);
}

#define GLDS(g, l)                                                              \
  __builtin_amdgcn_global_load_lds(                                             \
      (const __attribute__((address_space(1))) void*)(g),                       \
      (__attribute__((address_space(3))) void*)(l), 16, 0, 0)

// ---------------- f32 -> bf16 convert (n % 8 == 0) ----------------
__global__ void convert_bf16(const float* __restrict__ in, u16* __restrict__ out, int n) {
  int i = (blockIdx.x * blockDim.x + threadIdx.x) * 8;
  if (i >= n) return;
  float4 a = *(const float4*)(in + i);
  float4 b = *(const float4*)(in + i + 4);
  u16x8 r;
  r[0] = f2bf(a.x); r[1] = f2bf(a.y); r[2] = f2bf(a.z); r[3] = f2bf(a.w);
  r[4] = f2bf(b.x); r[5] = f2bf(b.y); r[6] = f2bf(b.z); r[7] = f2bf(b.w);
  *(u16x8*)(out + i) = r;
}

// ---------------- transpose + convert: out[C][R] = in[R][C]^T ----------------
__global__ void transpose_convert(const float* __restrict__ in, u16* __restrict__ out,
                                  int R, int C) {
  __shared__ float t[32][33];
  int bx = blockIdx.x * 32, by = blockIdx.y * 32;
  int x = threadIdx.x, y = threadIdx.y;  // block (32,8)
#pragma unroll
  for (int j = 0; j < 32; j += 8) t[y + j][x] = in[(size_t)(by + y + j) * C + bx + x];
  __syncthreads();
#pragma unroll
  for (int j = 0; j < 32; j += 8)
    out[(size_t)(bx + y + j) * R + by + x] = f2bf(t[x][y + j]);
}

// ---------------- concat bias: [WQ_b (1024), zeros (1024)] ----------------
__global__ void make_biascat(const float* __restrict__ qb_, float* __restrict__ out) {
  int i = blockIdx.x * 256 + threadIdx.x;  // 2048 total
  out[i] = (i < Dz) ? qb_[i] : 0.0f;
}

// ---------------- NT GEMM: C[M,N] = A[M,K](lda) * W[N,K]^T + bias ----------------
// m97 structure: 128x128 tile, BK=32, 4 waves (2x2), 16x16x32 bf16 MFMA,
// global_load_lds width-16 staging into linear LDS. XCD-bijective block swizzle.
// MODE 0: bf16 row-major out; MODE 1: f32 row-major out;
// MODE 2: bf16 out written V-transposed: Vt[bh][d][s] (bh=(row>>11)*16+(col>>6)).
template <int MODE>
__global__ __launch_bounds__(256) void gemm_nt(const u16* __restrict__ A,
                                               const u16* __restrict__ W,
                                               const float* __restrict__ bias,
                                               void* __restrict__ Cv,
                                               int M, int N, int K, int lda) {
  __shared__ u16 As[128 * 32];
  __shared__ u16 Bs[128 * 32];
  const int tid = threadIdx.x;
  const int wid = tid >> 6, lane = tid & 63;
  // XCD-aware bijective swizzle (all launches have nwg % 8 == 0)
  const int nwg = gridDim.x * gridDim.y;
  const int id = blockIdx.y * gridDim.x + blockIdx.x;
  const int swz = (id & 7) * (nwg >> 3) + (id >> 3);
  const int bx = swz % gridDim.x, by = swz / gridDim.x;
  const int row0 = by * 128, col0 = bx * 128;
  const int wm = (wid >> 1) * 64, wn = (wid & 1) * 64;
  f32x4 acc[4][4] = {};
  const int srow = lane >> 2, scol = (lane & 3) * 8;  // staging: 16 rows/KB, 4 lanes/row
  const int frow = lane & 15, fk = (lane >> 4) * 8;   // fragment addressing

  for (int k0 = 0; k0 < K; k0 += 32) {
    __syncthreads();
#pragma unroll
    for (int it = 0; it < 2; ++it) {
      int c = it * 4 + wid;  // 1KB chunk id, 8 chunks per 8KB tile
      const u16* ga = A + (size_t)(row0 + c * 16 + srow) * lda + k0 + scol;
      const u16* gb = W + (size_t)(col0 + c * 16 + srow) * K + k0 + scol;
      GLDS(ga, As + c * 512);
      GLDS(gb, Bs + c * 512);
    }
    __syncthreads();
    bf16x8 af[4], bfr[4];
#pragma unroll
    for (int m = 0; m < 4; ++m) af[m] = *(const bf16x8*)(As + (wm + m * 16 + frow) * 32 + fk);
#pragma unroll
    for (int n = 0; n < 4; ++n) bfr[n] = *(const bf16x8*)(Bs + (wn + n * 16 + frow) * 32 + fk);
#pragma unroll
    for (int m = 0; m < 4; ++m)
#pragma unroll
      for (int n = 0; n < 4; ++n)
        acc[m][n] = __builtin_amdgcn_mfma_f32_16x16x32_bf16(af[m], bfr[n], acc[m][n], 0, 0, 0);
  }

  const int r4 = (lane >> 4) * 4, cc = lane & 15;
#pragma unroll
  for (int m = 0; m < 4; ++m)
#pragma unroll
    for (int n = 0; n < 4; ++n) {
      int col = col0 + wn + n * 16 + cc;
      float bv = bias[col];
      if constexpr (MODE == 2) {
        int rowb = row0 + wm + m * 16 + r4;  // 4 consecutive rows, same b (no 2048 crossing)
        size_t obase = (size_t)((rowb >> 11) * Hz + (col >> 6)) * ((size_t)HDz * Sz) +
                       (size_t)(col & 63) * Sz + (rowb & 2047);
        u16x4 w4;
#pragma unroll
        for (int j = 0; j < 4; ++j) w4[j] = f2bf(acc[m][n][j] + bv);
        *(u16x4*)((u16*)Cv + obase) = w4;
      } else {
#pragma unroll
        for (int j = 0; j < 4; ++j) {
          int row = row0 + wm + m * 16 + r4 + j;
          float v = acc[m][n][j] + bv;
          if constexpr (MODE == 0)
            ((u16*)Cv)[(size_t)row * N + col] = f2bf(v);
          else
            ((float*)Cv)[(size_t)row * N + col] = v;
        }
      }
    }
}

// ---------------- causal flash attention (v3) ----------------
// grid: (S/128, B*H), heavy-blocks-first. block 256 = 4 waves; wave w owns
// 32 q rows [qb*128 + 32w, +32), KVBLK=64 staged in LDS.
// LDS tiles [64][64] u16, XOR-swizzled: byte ^= (row&7)<<4 (write AND read).
// Swapped QK^T: s = mfma(kf, qf) -> lane holds S^T[k=c*16+fhi*4+j][q=frow].
// Static-max softmax: p = exp2(s * (1/8)*log2(e)).
// Swapped PV: o = mfma(vf, pa) -> O^T[d][q]; denom on owning lane, contiguous-d
// 8B output stores.
__global__ __launch_bounds__(256, 4) void attn_kernel(const u16* __restrict__ Q,
                                                      const u16* __restrict__ Kg,
                                                      const u16* __restrict__ Vt,
                                                      u16* __restrict__ Og) {
  __shared__ __align__(16) u16 Ks[64 * 64];
  __shared__ __align__(16) u16 Vts[64 * 64];
  __shared__ __align__(16) u16 Ps[4][32 * 64];
  const int qb = (int)gridDim.x - 1 - (int)blockIdx.x;
  const int bh = blockIdx.y;
  const int tid = threadIdx.x, wid = tid >> 6, lane = tid & 63;
  const size_t kbase = (size_t)(bh >> 4) * Sz * Dz + (size_t)(bh & 15) * HDz;
  const size_t qbase = (size_t)(bh >> 4) * Sz * 2048 + (size_t)(bh & 15) * HDz;  // Q lda=2048
  const size_t vtb = (size_t)bh * HDz * Sz;
  const int frow = lane & 15, fhi = lane >> 4;
  const int q0 = qb * 128 + wid * 32;  // wave's first global q row

  // swizzled LDS address: row-major [*][64] u16 (128B rows)
  auto lsw = [](void* base, int row, int bo) -> void* {
    return (char*)base + (((row << 7) + bo) ^ ((row & 7) << 4));
  };

  // Q fragments (B-operand): q = q0 + qs*16 + frow, d = dc*32 + fhi*8 ..
  bf16x8 qf[2][2];
#pragma unroll
  for (int qs = 0; qs < 2; ++qs)
#pragma unroll
    for (int dc = 0; dc < 2; ++dc)
      qf[qs][dc] = *(const bf16x8*)(Q + qbase + (size_t)(q0 + qs * 16 + frow) * 2048 +
                                    dc * 32 + fhi * 8);

  f32x4 o[4][2] = {};
  float rs[2] = {0.0f, 0.0f};

  // staging: thread covers row r, bytes [cb, cb+32)
  const int r = tid >> 2, cb = (tid & 3) * 32;
  const u16* kgp = Kg + kbase + (size_t)r * Dz + (tid & 3) * 16;
  const u16* vgp = Vt + vtb + (size_t)r * Sz + (tid & 3) * 16;

  const int nt = 2 * qb + 2;
  u16x8 ka = *(const u16x8*)(kgp);
  u16x8 kb2 = *(const u16x8*)(kgp + 8);
  u16x8 va = *(const u16x8*)(vgp);
  u16x8 vb2 = *(const u16x8*)(vgp + 8);

  for (int t = 0; t < nt; ++t) {
    __syncthreads();  // previous tile's LDS reads done
    *(u16x8*)lsw(Ks, r, cb) = ka;
    *(u16x8*)lsw(Ks, r, cb + 16) = kb2;
    *(u16x8*)lsw(Vts, r, cb) = va;
    *(u16x8*)lsw(Vts, r, cb + 16) = vb2;
    if (t + 1 < nt) {  // T14: issue next-tile loads now, land during compute
      const size_t ko = (size_t)(t + 1) * 64 * Dz;
      const size_t vo = (size_t)(t + 1) * 64;
      ka = *(const u16x8*)(kgp + ko);
      kb2 = *(const u16x8*)(kgp + ko + 8);
      va = *(const u16x8*)(vgp + vo);
      vb2 = *(const u16x8*)(vgp + vo + 8);
    }
    __syncthreads();  // LDS ready

    if (64 * t > q0 + 31) continue;  // wave fully masked for this tile

    const bool dm = (t >= 2 * qb);
    const int koff = (t - 2 * qb) * 64;

#pragma unroll
    for (int qs = 0; qs < 2; ++qs) {
      f32x4 s[4] = {};
#pragma unroll
      for (int dc = 0; dc < 2; ++dc)
#pragma unroll
        for (int c = 0; c < 4; ++c) {
          bf16x8 kf = *(const bf16x8*)lsw(Ks, c * 16 + frow, dc * 64 + fhi * 16);
          s[c] = __builtin_amdgcn_mfma_f32_16x16x32_bf16(kf, qf[qs][dc], s[c], 0, 0, 0);
        }
      const int qloc = wid * 32 + qs * 16 + frow;
#pragma unroll
      for (int c = 0; c < 4; ++c) {
        bf16x4 w;
#pragma unroll
        for (int j = 0; j < 4; ++j) {
          float v = __builtin_exp2f(s[c][j] * 0.18033688f);  // fold 1/8 * log2(e)
          if (dm) v = ((koff + c * 16 + fhi * 4 + j) <= qloc) ? v : 0.0f;
          rs[qs] += v;
          w[j] = (__bf16)v;  // compiler -> v_cvt_pk_bf16_f32
        }
        *(bf16x4*)lsw(Ps[wid], qs * 16 + frow, c * 32 + fhi * 8) = w;
      }
    }

    // PV (O^T): o[n][qs] += V^T(d,k) * P^T->B(k,q)
#pragma unroll
    for (int kc = 0; kc < 2; ++kc) {
      bf16x8 pa0 = *(const bf16x8*)lsw(Ps[wid], frow, kc * 64 + fhi * 16);
      bf16x8 pa1 = *(const bf16x8*)lsw(Ps[wid], 16 + frow, kc * 64 + fhi * 16);
#pragma unroll
      for (int n = 0; n < 4; ++n) {
        bf16x8 vf = *(const bf16x8*)lsw(Vts, n * 16 + frow, kc * 64 + fhi * 16);
        o[n][0] = __builtin_amdgcn_mfma_f32_16x16x32_bf16(vf, pa0, o[n][0], 0, 0, 0);
        o[n][1] = __builtin_amdgcn_mfma_f32_16x16x32_bf16(vf, pa1, o[n][1], 0, 0, 0);
      }
    }
  }

  // epilogue: denom for q = q0+qs*16+frow lives on this lane after fhi-reduce
#pragma unroll
  for (int qs = 0; qs < 2; ++qs) {
    float l = rs[qs];
    l += __shfl_xor(l, 16);
    l += __shfl_xor(l, 32);
    float inv = 1.0f / l;
    const size_t ob = kbase + (size_t)(q0 + qs * 16 + frow) * Dz;
#pragma unroll
    for (int n = 0; n < 4; ++n) {
      bf16x4 w;
#pragma unroll
      for (int j = 0; j < 4; ++j) w[j] = (__bf16)(o[n][qs][j] * inv);
      *(bf16x4*)(Og + ob + n * 16 + fhi * 4) = w;
    }
  }
}

// ---------------- host launcher ----------------
extern "C" void kernel_launch(void* const* d_in, const int* in_sizes, int n_in,
                              void* d_out, int out_size, void* d_ws, size_t ws_size,
                              hipStream_t stream) {
  const float* hs    = (const float*)d_in[0];
  const float* WQ_w  = (const float*)d_in[1];
  const float* WQ_b  = (const float*)d_in[2];
  const float* WKA_w = (const float*)d_in[3];
  const float* WKB_w = (const float*)d_in[4];
  const float* WKB_b = (const float*)d_in[5];
  const float* WVA_w = (const float*)d_in[6];
  const float* WVB_w = (const float*)d_in[7];
  const float* WVB_b = (const float*)d_in[8];
  const float* WC_w  = (const float*)d_in[9];
  const float* WC_b  = (const float*)d_in[10];
  float* out = (float*)d_out;

  char* p = (char*)d_ws;
  auto alloc = [&](size_t bytes) {
    char* r = p;
    p += (bytes + 255) & ~(size_t)255;
    return r;
  };
  u16* hsb   = (u16*)alloc((size_t)Mz * Dz * 2);        // hs bf16; reused as attn out
  u16* wcat  = (u16*)alloc((size_t)2048 * Dz * 2);      // [WQ; WKA; WVA] rows
  u16* wkbb  = (u16*)alloc((size_t)Dz * Rz * 2);
  u16* wvbb  = (u16*)alloc((size_t)Dz * Rz * 2);
  u16* wcb   = (u16*)alloc((size_t)Dz * Dz * 2);        // c_proj_w transposed
  float* bcat = (float*)alloc((size_t)2048 * 4);        // [WQ_b, zeros]
  u16* QA    = (u16*)alloc((size_t)Mz * 2048 * 2);      // cols 0-1023: Q, 1024-2047: KA|VA
  u16* Kb    = (u16*)alloc((size_t)Mz * Dz * 2);
  u16* Vtg   = (u16*)alloc((size_t)Mz * Dz * 2);        // [bh][64][2048]
  u16* AOb   = hsb;                                     // attn out overwrites hs bf16

  // converts (weight concat: rows 0-1023=WQ, 1024-1535=WKA, 1536-2047=WVA)
  convert_bf16<<<(Mz * Dz) / 8 / 256, 256, 0, stream>>>(hs, hsb, Mz * Dz);
  convert_bf16<<<(Dz * Dz) / 8 / 256, 256, 0, stream>>>(WQ_w, wcat, Dz * Dz);
  convert_bf16<<<(Rz * Dz) / 8 / 256, 256, 0, stream>>>(WKA_w, wcat + (size_t)Dz * Dz, Rz * Dz);
  convert_bf16<<<(Rz * Dz) / 8 / 256, 256, 0, stream>>>(WVA_w, wcat + (size_t)1536 * Dz, Rz * Dz);
  convert_bf16<<<(Dz * Rz) / 8 / 256, 256, 0, stream>>>(WKB_w, wkbb, Dz * Rz);
  convert_bf16<<<(Dz * Rz) / 8 / 256, 256, 0, stream>>>(WVB_w, wvbb, Dz * Rz);
  transpose_convert<<<dim3(Dz / 32, Dz / 32), dim3(32, 8), 0, stream>>>(WC_w, wcb, Dz, Dz);
  make_biascat<<<8, 256, 0, stream>>>(WQ_b, bcat);

  // fused Q|KA|VA projection: QA[8192][2048] = hsb * wcat^T + bcat
  gemm_nt<0><<<dim3(2048 / 128, Mz / 128), 256, 0, stream>>>(hsb, wcat, bcat, QA,
                                                             Mz, 2048, Dz, Dz);
  // K = QA[:,1024:1536] * WK_B^T + b   (lda 2048)
  gemm_nt<0><<<dim3(Dz / 128, Mz / 128), 256, 0, stream>>>(QA + Dz, wkbb, WKB_b, Kb,
                                                           Mz, Dz, Rz, 2048);
  // V (written transposed): Vt[bh][d][s] = (QA[:,1536:2048] * WV_B^T + b)^T
  gemm_nt<2><<<dim3(Dz / 128, Mz / 128), 256, 0, stream>>>(QA + 1536, wvbb, WVB_b, Vtg,
                                                           Mz, Dz, Rz, 2048);

  // attention (Q from QA cols 0-1023, lda 2048)
  attn_kernel<<<dim3(Sz / 128, Bz * Hz), 256, 0, stream>>>(QA, Kb, Vtg, AOb);

  // output projection -> f32
  gemm_nt<1><<<dim3(Dz / 128, Mz / 128), 256, 0, stream>>>(AOb, wcb, WC_b, out,
                                                           Mz, Dz, Dz, Dz);
}

// Round 5
// 361.533 us; speedup vs baseline: 1.2201x; 1.2201x over previous
//
#include <hip/hip_runtime.h>

// Problem constants
#define Bz 4
#define Sz 2048
#define Dz 1024
#define Hz 16
#define HDz 64
#define Rz 512
#define Mz (Bz * Sz)  // 8192 total rows

typedef unsigned short u16;
typedef __bf16 bf16x8 __attribute__((ext_vector_type(8)));
typedef __bf16 bf16x4 __attribute__((ext_vector_type(4)));
typedef float f32x4 __attribute__((ext_vector_type(4)));
typedef u16 u16x8 __attribute__((ext_vector_type(8)));
typedef u16 u16x4 __attribute__((ext_vector_type(4)));

__device__ __forceinline__ u16 f2bf(float f) {
  unsigned u = __builtin_bit_cast(unsigned, f);
  u += 0x7fffu + ((u >> 16) & 1u);  // RNE
  return (u16)(u >> 16);
}

#define GLDS(g, l)                                                              \
  __builtin_amdgcn_global_load_lds(                                             \
      (const __attribute__((address_space(1))) void*)(g),                       \
      (__attribute__((address_space(3))) void*)(l), 16, 0, 0)

// ---------------- f32 -> bf16 convert (n % 8 == 0) ----------------
__global__ void convert_bf16(const float* __restrict__ in, u16* __restrict__ out, int n) {
  int i = (blockIdx.x * blockDim.x + threadIdx.x) * 8;
  if (i >= n) return;
  float4 a = *(const float4*)(in + i);
  float4 b = *(const float4*)(in + i + 4);
  u16x8 r;
  r[0] = f2bf(a.x); r[1] = f2bf(a.y); r[2] = f2bf(a.z); r[3] = f2bf(a.w);
  r[4] = f2bf(b.x); r[5] = f2bf(b.y); r[6] = f2bf(b.z); r[7] = f2bf(b.w);
  *(u16x8*)(out + i) = r;
}

// ---------------- transpose + convert: out[C][R] = in[R][C]^T ----------------
__global__ void transpose_convert(const float* __restrict__ in, u16* __restrict__ out,
                                  int R, int C) {
  __shared__ float t[32][33];
  int bx = blockIdx.x * 32, by = blockIdx.y * 32;
  int x = threadIdx.x, y = threadIdx.y;  // block (32,8)
#pragma unroll
  for (int j = 0; j < 32; j += 8) t[y + j][x] = in[(size_t)(by + y + j) * C + bx + x];
  __syncthreads();
#pragma unroll
  for (int j = 0; j < 32; j += 8)
    out[(size_t)(bx + y + j) * R + by + x] = f2bf(t[x][y + j]);
}

// ---------------- concat bias: [WQ_b (1024), zeros (1024)] ----------------
__global__ void make_biascat(const float* __restrict__ qb_, float* __restrict__ out) {
  int i = blockIdx.x * 256 + threadIdx.x;  // 2048 total
  out[i] = (i < Dz) ? qb_[i] : 0.0f;
}

// ---------------- NT GEMM: C[M,N] = A[M,K](lda) * W[N,K]^T + bias ----------------
// m97 structure: 128x128 tile, BK=32, 4 waves (2x2), 16x16x32 bf16 MFMA,
// global_load_lds width-16 staging into linear LDS. XCD-bijective block swizzle.
// MODE 0: bf16 row-major out; MODE 1: f32 row-major out;
// MODE 2: bf16 out written V-transposed: Vt[bh][d][s] (bh=(row>>11)*16+(col>>6)).
template <int MODE>
__global__ __launch_bounds__(256) void gemm_nt(const u16* __restrict__ A,
                                               const u16* __restrict__ W,
                                               const float* __restrict__ bias,
                                               void* __restrict__ Cv,
                                               int M, int N, int K, int lda) {
  __shared__ u16 As[128 * 32];
  __shared__ u16 Bs[128 * 32];
  const int tid = threadIdx.x;
  const int wid = tid >> 6, lane = tid & 63;
  // XCD-aware bijective swizzle (all launches have nwg % 8 == 0)
  const int nwg = gridDim.x * gridDim.y;
  const int id = blockIdx.y * gridDim.x + blockIdx.x;
  const int swz = (id & 7) * (nwg >> 3) + (id >> 3);
  const int bx = swz % gridDim.x, by = swz / gridDim.x;
  const int row0 = by * 128, col0 = bx * 128;
  const int wm = (wid >> 1) * 64, wn = (wid & 1) * 64;
  f32x4 acc[4][4] = {};
  const int srow = lane >> 2, scol = (lane & 3) * 8;  // staging: 16 rows/KB, 4 lanes/row
  const int frow = lane & 15, fk = (lane >> 4) * 8;   // fragment addressing

  for (int k0 = 0; k0 < K; k0 += 32) {
    __syncthreads();
#pragma unroll
    for (int it = 0; it < 2; ++it) {
      int c = it * 4 + wid;  // 1KB chunk id, 8 chunks per 8KB tile
      const u16* ga = A + (size_t)(row0 + c * 16 + srow) * lda + k0 + scol;
      const u16* gb = W + (size_t)(col0 + c * 16 + srow) * K + k0 + scol;
      GLDS(ga, As + c * 512);
      GLDS(gb, Bs + c * 512);
    }
    __syncthreads();
    bf16x8 af[4], bfr[4];
#pragma unroll
    for (int m = 0; m < 4; ++m) af[m] = *(const bf16x8*)(As + (wm + m * 16 + frow) * 32 + fk);
#pragma unroll
    for (int n = 0; n < 4; ++n) bfr[n] = *(const bf16x8*)(Bs + (wn + n * 16 + frow) * 32 + fk);
#pragma unroll
    for (int m = 0; m < 4; ++m)
#pragma unroll
      for (int n = 0; n < 4; ++n)
        acc[m][n] = __builtin_amdgcn_mfma_f32_16x16x32_bf16(af[m], bfr[n], acc[m][n], 0, 0, 0);
  }

  const int r4 = (lane >> 4) * 4, cc = lane & 15;
#pragma unroll
  for (int m = 0; m < 4; ++m)
#pragma unroll
    for (int n = 0; n < 4; ++n) {
      int col = col0 + wn + n * 16 + cc;
      float bv = bias[col];
      if constexpr (MODE == 2) {
        int rowb = row0 + wm + m * 16 + r4;  // 4 consecutive rows, same b (no 2048 crossing)
        size_t obase = (size_t)((rowb >> 11) * Hz + (col >> 6)) * ((size_t)HDz * Sz) +
                       (size_t)(col & 63) * Sz + (rowb & 2047);
        u16x4 w4;
#pragma unroll
        for (int j = 0; j < 4; ++j) w4[j] = f2bf(acc[m][n][j] + bv);
        *(u16x4*)((u16*)Cv + obase) = w4;
      } else {
#pragma unroll
        for (int j = 0; j < 4; ++j) {
          int row = row0 + wm + m * 16 + r4 + j;
          float v = acc[m][n][j] + bv;
          if constexpr (MODE == 0)
            ((u16*)Cv)[(size_t)row * N + col] = f2bf(v);
          else
            ((float*)Cv)[(size_t)row * N + col] = v;
        }
      }
    }
}

// ---------------- causal flash attention (v3.1) ----------------
// grid: (S/128, B*H), heavy-blocks-first. block 256 = 4 waves; wave w owns
// 32 q rows [qb*128 + 32w, +32), KVBLK=64 staged in LDS.
// LDS tiles [64][64] u16, XOR-swizzled: byte ^= (row&7)<<4 (write AND read).
// Swapped QK^T: s = mfma(kf, qf) -> lane holds S^T[k=c*16+fhi*4+j][q=frow].
// Static-max softmax: p = exp2(s * (1/8)*log2(e)).
// Swapped PV: o = mfma(vf, pa) -> O^T[d][q]; denom on owning lane, contiguous-d
// 8B output stores.
// v3.1: __launch_bounds__(256,2) — R4's (256,4) capped VGPR at 64 < ~80 live
// -> per-iter scratch spills (WRITE_SIZE 16->154 MB, dur +47%). Occupancy is
// LDS-bound (32KB/block) so the higher VGPR count is free.
__global__ __launch_bounds__(256, 2) void attn_kernel(const u16* __restrict__ Q,
                                                      const u16* __restrict__ Kg,
                                                      const u16* __restrict__ Vt,
                                                      u16* __restrict__ Og) {
  __shared__ __align__(16) u16 Ks[64 * 64];
  __shared__ __align__(16) u16 Vts[64 * 64];
  __shared__ __align__(16) u16 Ps[4][32 * 64];
  const int qb = (int)gridDim.x - 1 - (int)blockIdx.x;
  const int bh = blockIdx.y;
  const int tid = threadIdx.x, wid = tid >> 6, lane = tid & 63;
  const size_t kbase = (size_t)(bh >> 4) * Sz * Dz + (size_t)(bh & 15) * HDz;
  const size_t qbase = (size_t)(bh >> 4) * Sz * 2048 + (size_t)(bh & 15) * HDz;  // Q lda=2048
  const size_t vtb = (size_t)bh * HDz * Sz;
  const int frow = lane & 15, fhi = lane >> 4;
  const int q0 = qb * 128 + wid * 32;  // wave's first global q row

  // swizzled LDS address: row-major [*][64] u16 (128B rows)
  auto lsw = [](void* base, int row, int bo) -> void* {
    return (char*)base + (((row << 7) + bo) ^ ((row & 7) << 4));
  };

  // Q fragments (B-operand): q = q0 + qs*16 + frow, d = dc*32 + fhi*8 ..
  bf16x8 qf[2][2];
#pragma unroll
  for (int qs = 0; qs < 2; ++qs)
#pragma unroll
    for (int dc = 0; dc < 2; ++dc)
      qf[qs][dc] = *(const bf16x8*)(Q + qbase + (size_t)(q0 + qs * 16 + frow) * 2048 +
                                    dc * 32 + fhi * 8);

  f32x4 o[4][2] = {};
  float rs[2] = {0.0f, 0.0f};

  // staging: thread covers row r, bytes [cb, cb+32)
  const int r = tid >> 2, cb = (tid & 3) * 32;
  const u16* kgp = Kg + kbase + (size_t)r * Dz + (tid & 3) * 16;
  const u16* vgp = Vt + vtb + (size_t)r * Sz + (tid & 3) * 16;

  const int nt = 2 * qb + 2;
  u16x8 ka = *(const u16x8*)(kgp);
  u16x8 kb2 = *(const u16x8*)(kgp + 8);
  u16x8 va = *(const u16x8*)(vgp);
  u16x8 vb2 = *(const u16x8*)(vgp + 8);

  for (int t = 0; t < nt; ++t) {
    __syncthreads();  // previous tile's LDS reads done
    *(u16x8*)lsw(Ks, r, cb) = ka;
    *(u16x8*)lsw(Ks, r, cb + 16) = kb2;
    *(u16x8*)lsw(Vts, r, cb) = va;
    *(u16x8*)lsw(Vts, r, cb + 16) = vb2;
    if (t + 1 < nt) {  // T14: issue next-tile loads now, land during compute
      const size_t ko = (size_t)(t + 1) * 64 * Dz;
      const size_t vo = (size_t)(t + 1) * 64;
      ka = *(const u16x8*)(kgp + ko);
      kb2 = *(const u16x8*)(kgp + ko + 8);
      va = *(const u16x8*)(vgp + vo);
      vb2 = *(const u16x8*)(vgp + vo + 8);
    }
    __syncthreads();  // LDS ready

    if (64 * t > q0 + 31) continue;  // wave fully masked for this tile

    const bool dm = (t >= 2 * qb);
    const int koff = (t - 2 * qb) * 64;

#pragma unroll
    for (int qs = 0; qs < 2; ++qs) {
      f32x4 s[4] = {};
#pragma unroll
      for (int dc = 0; dc < 2; ++dc)
#pragma unroll
        for (int c = 0; c < 4; ++c) {
          bf16x8 kf = *(const bf16x8*)lsw(Ks, c * 16 + frow, dc * 64 + fhi * 16);
          s[c] = __builtin_amdgcn_mfma_f32_16x16x32_bf16(kf, qf[qs][dc], s[c], 0, 0, 0);
        }
      const int qloc = wid * 32 + qs * 16 + frow;
#pragma unroll
      for (int c = 0; c < 4; ++c) {
        bf16x4 w;
#pragma unroll
        for (int j = 0; j < 4; ++j) {
          float v = __builtin_exp2f(s[c][j] * 0.18033688f);  // fold 1/8 * log2(e)
          if (dm) v = ((koff + c * 16 + fhi * 4 + j) <= qloc) ? v : 0.0f;
          rs[qs] += v;
          w[j] = (__bf16)v;  // compiler -> v_cvt_pk_bf16_f32
        }
        *(bf16x4*)lsw(Ps[wid], qs * 16 + frow, c * 32 + fhi * 8) = w;
      }
    }

    // PV (O^T): o[n][qs] += V^T(d,k) * P^T->B(k,q)
#pragma unroll
    for (int kc = 0; kc < 2; ++kc) {
      bf16x8 pa0 = *(const bf16x8*)lsw(Ps[wid], frow, kc * 64 + fhi * 16);
      bf16x8 pa1 = *(const bf16x8*)lsw(Ps[wid], 16 + frow, kc * 64 + fhi * 16);
#pragma unroll
      for (int n = 0; n < 4; ++n) {
        bf16x8 vf = *(const bf16x8*)lsw(Vts, n * 16 + frow, kc * 64 + fhi * 16);
        o[n][0] = __builtin_amdgcn_mfma_f32_16x16x32_bf16(vf, pa0, o[n][0], 0, 0, 0);
        o[n][1] = __builtin_amdgcn_mfma_f32_16x16x32_bf16(vf, pa1, o[n][1], 0, 0, 0);
      }
    }
  }

  // epilogue: denom for q = q0+qs*16+frow lives on this lane after fhi-reduce
#pragma unroll
  for (int qs = 0; qs < 2; ++qs) {
    float l = rs[qs];
    l += __shfl_xor(l, 16);
    l += __shfl_xor(l, 32);
    float inv = 1.0f / l;
    const size_t ob = kbase + (size_t)(q0 + qs * 16 + frow) * Dz;
#pragma unroll
    for (int n = 0; n < 4; ++n) {
      bf16x4 w;
#pragma unroll
      for (int j = 0; j < 4; ++j) w[j] = (__bf16)(o[n][qs][j] * inv);
      *(bf16x4*)(Og + ob + n * 16 + fhi * 4) = w;
    }
  }
}

// ---------------- host launcher ----------------
extern "C" void kernel_launch(void* const* d_in, const int* in_sizes, int n_in,
                              void* d_out, int out_size, void* d_ws, size_t ws_size,
                              hipStream_t stream) {
  const float* hs    = (const float*)d_in[0];
  const float* WQ_w  = (const float*)d_in[1];
  const float* WQ_b  = (const float*)d_in[2];
  const float* WKA_w = (const float*)d_in[3];
  const float* WKB_w = (const float*)d_in[4];
  const float* WKB_b = (const float*)d_in[5];
  const float* WVA_w = (const float*)d_in[6];
  const float* WVB_w = (const float*)d_in[7];
  const float* WVB_b = (const float*)d_in[8];
  const float* WC_w  = (const float*)d_in[9];
  const float* WC_b  = (const float*)d_in[10];
  float* out = (float*)d_out;

  char* p = (char*)d_ws;
  auto alloc = [&](size_t bytes) {
    char* r = p;
    p += (bytes + 255) & ~(size_t)255;
    return r;
  };
  u16* hsb   = (u16*)alloc((size_t)Mz * Dz * 2);        // hs bf16; reused as attn out
  u16* wcat  = (u16*)alloc((size_t)2048 * Dz * 2);      // [WQ; WKA; WVA] rows
  u16* wkbb  = (u16*)alloc((size_t)Dz * Rz * 2);
  u16* wvbb  = (u16*)alloc((size_t)Dz * Rz * 2);
  u16* wcb   = (u16*)alloc((size_t)Dz * Dz * 2);        // c_proj_w transposed
  float* bcat = (float*)alloc((size_t)2048 * 4);        // [WQ_b, zeros]
  u16* QA    = (u16*)alloc((size_t)Mz * 2048 * 2);      // cols 0-1023: Q, 1024-2047: KA|VA
  u16* Kb    = (u16*)alloc((size_t)Mz * Dz * 2);
  u16* Vtg   = (u16*)alloc((size_t)Mz * Dz * 2);        // [bh][64][2048]
  u16* AOb   = hsb;                                     // attn out overwrites hs bf16

  // converts (weight concat: rows 0-1023=WQ, 1024-1535=WKA, 1536-2047=WVA)
  convert_bf16<<<(Mz * Dz) / 8 / 256, 256, 0, stream>>>(hs, hsb, Mz * Dz);
  convert_bf16<<<(Dz * Dz) / 8 / 256, 256, 0, stream>>>(WQ_w, wcat, Dz * Dz);
  convert_bf16<<<(Rz * Dz) / 8 / 256, 256, 0, stream>>>(WKA_w, wcat + (size_t)Dz * Dz, Rz * Dz);
  convert_bf16<<<(Rz * Dz) / 8 / 256, 256, 0, stream>>>(WVA_w, wcat + (size_t)1536 * Dz, Rz * Dz);
  convert_bf16<<<(Dz * Rz) / 8 / 256, 256, 0, stream>>>(WKB_w, wkbb, Dz * Rz);
  convert_bf16<<<(Dz * Rz) / 8 / 256, 256, 0, stream>>>(WVB_w, wvbb, Dz * Rz);
  transpose_convert<<<dim3(Dz / 32, Dz / 32), dim3(32, 8), 0, stream>>>(WC_w, wcb, Dz, Dz);
  make_biascat<<<8, 256, 0, stream>>>(WQ_b, bcat);

  // fused Q|KA|VA projection: QA[8192][2048] = hsb * wcat^T + bcat
  gemm_nt<0><<<dim3(2048 / 128, Mz / 128), 256, 0, stream>>>(hsb, wcat, bcat, QA,
                                                             Mz, 2048, Dz, Dz);
  // K = QA[:,1024:1536] * WK_B^T + b   (lda 2048)
  gemm_nt<0><<<dim3(Dz / 128, Mz / 128), 256, 0, stream>>>(QA + Dz, wkbb, WKB_b, Kb,
                                                           Mz, Dz, Rz, 2048);
  // V (written transposed): Vt[bh][d][s] = (QA[:,1536:2048] * WV_B^T + b)^T
  gemm_nt<2><<<dim3(Dz / 128, Mz / 128), 256, 0, stream>>>(QA + 1536, wvbb, WVB_b, Vtg,
                                                           Mz, Dz, Rz, 2048);

  // attention (Q from QA cols 0-1023, lda 2048)
  attn_kernel<<<dim3(Sz / 128, Bz * Hz), 256, 0, stream>>>(QA, Kb, Vtg, AOb);

  // output projection -> f32
  gemm_nt<1><<<dim3(Dz / 128, Mz / 128), 256, 0, stream>>>(AOb, wcb, WC_b, out,
                                                           Mz, Dz, Dz, Dz);
}

// Round 6
// 311.323 us; speedup vs baseline: 1.4169x; 1.1613x over previous
//
#include <hip/hip_runtime.h>

// Problem constants
#define Bz 4
#define Sz 2048
#define Dz 1024
#define Hz 16
#define HDz 64
#define Rz 512
#define Mz (Bz * Sz)  // 8192 total rows

typedef unsigned short u16;
typedef __bf16 bf16x8 __attribute__((ext_vector_type(8)));
typedef __bf16 bf16x4 __attribute__((ext_vector_type(4)));
typedef float f32x4 __attribute__((ext_vector_type(4)));
typedef u16 u16x8 __attribute__((ext_vector_type(8)));
typedef u16 u16x4 __attribute__((ext_vector_type(4)));

__device__ __forceinline__ u16 f2bf(float f) {
  unsigned u = __builtin_bit_cast(unsigned, f);
  u += 0x7fffu + ((u >> 16) & 1u);  // RNE
  return (u16)(u >> 16);
}

#define GLDS(g, l)                                                              \
  __builtin_amdgcn_global_load_lds(                                             \
      (const __attribute__((address_space(1))) void*)(g),                       \
      (__attribute__((address_space(3))) void*)(l), 16, 0, 0)

// ---------------- f32 -> bf16 convert (n % 8 == 0) ----------------
__global__ void convert_bf16(const float* __restrict__ in, u16* __restrict__ out, int n) {
  int i = (blockIdx.x * blockDim.x + threadIdx.x) * 8;
  if (i >= n) return;
  float4 a = *(const float4*)(in + i);
  float4 b = *(const float4*)(in + i + 4);
  u16x8 r;
  r[0] = f2bf(a.x); r[1] = f2bf(a.y); r[2] = f2bf(a.z); r[3] = f2bf(a.w);
  r[4] = f2bf(b.x); r[5] = f2bf(b.y); r[6] = f2bf(b.z); r[7] = f2bf(b.w);
  *(u16x8*)(out + i) = r;
}

// ---------------- transpose + convert: out[C][R] = in[R][C]^T ----------------
__global__ void transpose_convert(const float* __restrict__ in, u16* __restrict__ out,
                                  int R, int C) {
  __shared__ float t[32][33];
  int bx = blockIdx.x * 32, by = blockIdx.y * 32;
  int x = threadIdx.x, y = threadIdx.y;  // block (32,8)
#pragma unroll
  for (int j = 0; j < 32; j += 8) t[y + j][x] = in[(size_t)(by + y + j) * C + bx + x];
  __syncthreads();
#pragma unroll
  for (int j = 0; j < 32; j += 8)
    out[(size_t)(bx + y + j) * R + by + x] = f2bf(t[x][y + j]);
}

// ---------------- concat bias: [WQ_b (1024), zeros (1024)] ----------------
__global__ void make_biascat(const float* __restrict__ qb_, float* __restrict__ out) {
  int i = blockIdx.x * 256 + threadIdx.x;  // 2048 total
  out[i] = (i < Dz) ? qb_[i] : 0.0f;
}

// ---------------- NT GEMM: C[M,N] = A[M,K](lda) * W[N,K]^T + bias ----------------
// m97 structure: 128x128 tile, BK=32, 4 waves (2x2), 16x16x32 bf16 MFMA,
// global_load_lds width-16 staging into linear LDS. XCD-bijective block swizzle.
// MODE 0: bf16 row-major out; MODE 1: f32 row-major out;
// MODE 2: bf16 out written V-transposed: Vt[bh][d][s] (bh=(row>>11)*16+(col>>6)).
template <int MODE>
__global__ __launch_bounds__(256) void gemm_nt(const u16* __restrict__ A,
                                               const u16* __restrict__ W,
                                               const float* __restrict__ bias,
                                               void* __restrict__ Cv,
                                               int M, int N, int K, int lda) {
  __shared__ u16 As[128 * 32];
  __shared__ u16 Bs[128 * 32];
  const int tid = threadIdx.x;
  const int wid = tid >> 6, lane = tid & 63;
  // XCD-aware bijective swizzle (all launches have nwg % 8 == 0)
  const int nwg = gridDim.x * gridDim.y;
  const int id = blockIdx.y * gridDim.x + blockIdx.x;
  const int swz = (id & 7) * (nwg >> 3) + (id >> 3);
  const int bx = swz % gridDim.x, by = swz / gridDim.x;
  const int row0 = by * 128, col0 = bx * 128;
  const int wm = (wid >> 1) * 64, wn = (wid & 1) * 64;
  f32x4 acc[4][4] = {};
  const int srow = lane >> 2, scol = (lane & 3) * 8;  // staging: 16 rows/KB, 4 lanes/row
  const int frow = lane & 15, fk = (lane >> 4) * 8;   // fragment addressing

  for (int k0 = 0; k0 < K; k0 += 32) {
    __syncthreads();
#pragma unroll
    for (int it = 0; it < 2; ++it) {
      int c = it * 4 + wid;  // 1KB chunk id, 8 chunks per 8KB tile
      const u16* ga = A + (size_t)(row0 + c * 16 + srow) * lda + k0 + scol;
      const u16* gb = W + (size_t)(col0 + c * 16 + srow) * K + k0 + scol;
      GLDS(ga, As + c * 512);
      GLDS(gb, Bs + c * 512);
    }
    __syncthreads();
    bf16x8 af[4], bfr[4];
#pragma unroll
    for (int m = 0; m < 4; ++m) af[m] = *(const bf16x8*)(As + (wm + m * 16 + frow) * 32 + fk);
#pragma unroll
    for (int n = 0; n < 4; ++n) bfr[n] = *(const bf16x8*)(Bs + (wn + n * 16 + frow) * 32 + fk);
#pragma unroll
    for (int m = 0; m < 4; ++m)
#pragma unroll
      for (int n = 0; n < 4; ++n)
        acc[m][n] = __builtin_amdgcn_mfma_f32_16x16x32_bf16(af[m], bfr[n], acc[m][n], 0, 0, 0);
  }

  const int r4 = (lane >> 4) * 4, cc = lane & 15;
#pragma unroll
  for (int m = 0; m < 4; ++m)
#pragma unroll
    for (int n = 0; n < 4; ++n) {
      int col = col0 + wn + n * 16 + cc;
      float bv = bias[col];
      if constexpr (MODE == 2) {
        int rowb = row0 + wm + m * 16 + r4;  // 4 consecutive rows, same b (no 2048 crossing)
        size_t obase = (size_t)((rowb >> 11) * Hz + (col >> 6)) * ((size_t)HDz * Sz) +
                       (size_t)(col & 63) * Sz + (rowb & 2047);
        u16x4 w4;
#pragma unroll
        for (int j = 0; j < 4; ++j) w4[j] = f2bf(acc[m][n][j] + bv);
        *(u16x4*)((u16*)Cv + obase) = w4;
      } else {
#pragma unroll
        for (int j = 0; j < 4; ++j) {
          int row = row0 + wm + m * 16 + r4 + j;
          float v = acc[m][n][j] + bv;
          if constexpr (MODE == 0)
            ((u16*)Cv)[(size_t)row * N + col] = f2bf(v);
          else
            ((float*)Cv)[(size_t)row * N + col] = v;
        }
      }
    }
}

// swizzled LDS address: row-major [*][64] u16 (128B rows), byte ^= (row&7)<<4
__device__ __forceinline__ void* lsw(void* base, int row, int bo) {
  return (char*)base + (((row << 7) + bo) ^ ((row & 7) << 4));
}

// one q-tile x k-tile step: QK^T (swapped), static-max softmax, PV (swapped).
// MASK: compile-time diagonal specialization (koff = k-offset within q-tile).
template <bool MASK>
__device__ __forceinline__ void tile_step(u16* Ks, u16* Vts, u16* Pw,
                                          int frow, int fhi, int qlocb, int koff,
                                          const bf16x8 (&qf)[2][2],
                                          f32x4 (&o)[4][2], float* rs) {
#pragma unroll
  for (int qs = 0; qs < 2; ++qs) {
    f32x4 s[4] = {};
#pragma unroll
    for (int dc = 0; dc < 2; ++dc)
#pragma unroll
      for (int c = 0; c < 4; ++c) {
        bf16x8 kf = *(const bf16x8*)lsw(Ks, c * 16 + frow, dc * 64 + fhi * 16);
        s[c] = __builtin_amdgcn_mfma_f32_16x16x32_bf16(kf, qf[qs][dc], s[c], 0, 0, 0);
      }
    const int qloc = qlocb + qs * 16 + frow;
#pragma unroll
    for (int c = 0; c < 4; ++c) {
      bf16x4 w;
#pragma unroll
      for (int j = 0; j < 4; ++j) {
        float v = __builtin_exp2f(s[c][j] * 0.18033688f);  // fold 1/8 * log2(e)
        if (MASK) v = ((koff + c * 16 + fhi * 4 + j) <= qloc) ? v : 0.0f;
        rs[qs] += v;
        w[j] = (__bf16)v;  // compiler -> v_cvt_pk_bf16_f32
      }
      *(bf16x4*)lsw(Pw, qs * 16 + frow, c * 32 + fhi * 8) = w;
    }
  }
#pragma unroll
  for (int kc = 0; kc < 2; ++kc) {
    bf16x8 pa0 = *(const bf16x8*)lsw(Pw, frow, kc * 64 + fhi * 16);
    bf16x8 pa1 = *(const bf16x8*)lsw(Pw, 16 + frow, kc * 64 + fhi * 16);
#pragma unroll
    for (int n = 0; n < 4; ++n) {
      bf16x8 vf = *(const bf16x8*)lsw(Vts, n * 16 + frow, kc * 64 + fhi * 16);
      o[n][0] = __builtin_amdgcn_mfma_f32_16x16x32_bf16(vf, pa0, o[n][0], 0, 0, 0);
      o[n][1] = __builtin_amdgcn_mfma_f32_16x16x32_bf16(vf, pa1, o[n][1], 0, 0, 0);
    }
  }
}

// ---------------- causal flash attention (v4: paired q-tiles) ----------------
// grid: (8, B*H). Block p handles q-tiles qA=p (light) and qB=15-p (heavy):
// per-block compute = (2p+2)+(32-2p) = 34 q-k-tiles, UNIFORM across blocks
// (fixes R5's 13.5% occupancy: tail of heavy blocks at ~1 wave/SIMD).
// While both tiles are active, one staged K/V tile feeds 2x MFMA work.
// 512 blocks = exactly 2/CU resident start-to-finish.
// LDS tiles [64][64] u16 XOR-swizzled; swapped QK^T / PV; static-max softmax;
// Ps region reused sequentially by B then A (same-wave RAW, lgkmcnt-ordered).
__global__ __launch_bounds__(256, 2) void attn_kernel(const u16* __restrict__ Q,
                                                      const u16* __restrict__ Kg,
                                                      const u16* __restrict__ Vt,
                                                      u16* __restrict__ Og) {
  __shared__ __align__(16) u16 Ks[64 * 64];
  __shared__ __align__(16) u16 Vts[64 * 64];
  __shared__ __align__(16) u16 Ps[4][32 * 64];
  const int pr = blockIdx.x;               // 0..7
  const int qA = pr, qB = 15 - pr;         // light, heavy q-tile indices
  const int bh = blockIdx.y;
  const int tid = threadIdx.x, wid = tid >> 6, lane = tid & 63;
  const size_t kbase = (size_t)(bh >> 4) * Sz * Dz + (size_t)(bh & 15) * HDz;
  const size_t qbase = (size_t)(bh >> 4) * Sz * 2048 + (size_t)(bh & 15) * HDz;  // Q lda=2048
  const size_t vtb = (size_t)bh * HDz * Sz;
  const int frow = lane & 15, fhi = lane >> 4;
  const int q0A = qA * 128 + wid * 32, q0B = qB * 128 + wid * 32;

  bf16x8 qfA[2][2], qfB[2][2];
#pragma unroll
  for (int qs = 0; qs < 2; ++qs)
#pragma unroll
    for (int dc = 0; dc < 2; ++dc) {
      qfA[qs][dc] = *(const bf16x8*)(Q + qbase + (size_t)(q0A + qs * 16 + frow) * 2048 +
                                     dc * 32 + fhi * 8);
      qfB[qs][dc] = *(const bf16x8*)(Q + qbase + (size_t)(q0B + qs * 16 + frow) * 2048 +
                                     dc * 32 + fhi * 8);
    }

  f32x4 oA[4][2] = {}, oB[4][2] = {};
  float rsA[2] = {0.0f, 0.0f}, rsB[2] = {0.0f, 0.0f};

  // staging: thread covers row r, bytes [cb, cb+32)
  const int r = tid >> 2, cb = (tid & 3) * 32;
  const u16* kgp = Kg + kbase + (size_t)r * Dz + (tid & 3) * 16;
  const u16* vgp = Vt + vtb + (size_t)r * Sz + (tid & 3) * 16;

  const int ntB = 2 * qB + 2;
  u16x8 ka = *(const u16x8*)(kgp);
  u16x8 kb2 = *(const u16x8*)(kgp + 8);
  u16x8 va = *(const u16x8*)(vgp);
  u16x8 vb2 = *(const u16x8*)(vgp + 8);

  for (int t = 0; t < ntB; ++t) {
    __syncthreads();  // previous tile's LDS reads done
    *(u16x8*)lsw(Ks, r, cb) = ka;
    *(u16x8*)lsw(Ks, r, cb + 16) = kb2;
    *(u16x8*)lsw(Vts, r, cb) = va;
    *(u16x8*)lsw(Vts, r, cb + 16) = vb2;
    if (t + 1 < ntB) {  // T14: issue next-tile loads now, land during compute
      const size_t ko = (size_t)(t + 1) * 64 * Dz;
      const size_t vo = (size_t)(t + 1) * 64;
      ka = *(const u16x8*)(kgp + ko);
      kb2 = *(const u16x8*)(kgp + ko + 8);
      va = *(const u16x8*)(vgp + vo);
      vb2 = *(const u16x8*)(vgp + vo + 8);
    }
    __syncthreads();  // LDS ready

    // heavy tile B (active for all t up to its diagonal)
    if (64 * t <= q0B + 31) {
      if (t >= 2 * qB)
        tile_step<true>(Ks, Vts, Ps[wid], frow, fhi, wid * 32, (t - 2 * qB) * 64,
                        qfB, oB, rsB);
      else
        tile_step<false>(Ks, Vts, Ps[wid], frow, fhi, wid * 32, 0, qfB, oB, rsB);
    }
    // light tile A (active only for t <= 2*qA+1)
    if (64 * t <= q0A + 31) {
      if (t >= 2 * qA)
        tile_step<true>(Ks, Vts, Ps[wid], frow, fhi, wid * 32, (t - 2 * qA) * 64,
                        qfA, oA, rsA);
      else
        tile_step<false>(Ks, Vts, Ps[wid], frow, fhi, wid * 32, 0, qfA, oA, rsA);
    }
  }

  // epilogue: denom for q = q0+qs*16+frow lives on this lane after fhi-reduce
#pragma unroll
  for (int x = 0; x < 2; ++x) {
    f32x4(&o)[4][2] = x ? oA : oB;
    float* rs = x ? rsA : rsB;
    const int q0 = x ? q0A : q0B;
#pragma unroll
    for (int qs = 0; qs < 2; ++qs) {
      float l = rs[qs];
      l += __shfl_xor(l, 16);
      l += __shfl_xor(l, 32);
      float inv = 1.0f / l;
      const size_t ob = kbase + (size_t)(q0 + qs * 16 + frow) * Dz;
#pragma unroll
      for (int n = 0; n < 4; ++n) {
        bf16x4 w;
#pragma unroll
        for (int j = 0; j < 4; ++j) w[j] = (__bf16)(o[n][qs][j] * inv);
        *(bf16x4*)(Og + ob + n * 16 + fhi * 4) = w;
      }
    }
  }
}

// ---------------- host launcher ----------------
extern "C" void kernel_launch(void* const* d_in, const int* in_sizes, int n_in,
                              void* d_out, int out_size, void* d_ws, size_t ws_size,
                              hipStream_t stream) {
  const float* hs    = (const float*)d_in[0];
  const float* WQ_w  = (const float*)d_in[1];
  const float* WQ_b  = (const float*)d_in[2];
  const float* WKA_w = (const float*)d_in[3];
  const float* WKB_w = (const float*)d_in[4];
  const float* WKB_b = (const float*)d_in[5];
  const float* WVA_w = (const float*)d_in[6];
  const float* WVB_w = (const float*)d_in[7];
  const float* WVB_b = (const float*)d_in[8];
  const float* WC_w  = (const float*)d_in[9];
  const float* WC_b  = (const float*)d_in[10];
  float* out = (float*)d_out;

  char* p = (char*)d_ws;
  auto alloc = [&](size_t bytes) {
    char* r = p;
    p += (bytes + 255) & ~(size_t)255;
    return r;
  };
  u16* hsb   = (u16*)alloc((size_t)Mz * Dz * 2);        // hs bf16; reused as attn out
  u16* wcat  = (u16*)alloc((size_t)2048 * Dz * 2);      // [WQ; WKA; WVA] rows
  u16* wkbb  = (u16*)alloc((size_t)Dz * Rz * 2);
  u16* wvbb  = (u16*)alloc((size_t)Dz * Rz * 2);
  u16* wcb   = (u16*)alloc((size_t)Dz * Dz * 2);        // c_proj_w transposed
  float* bcat = (float*)alloc((size_t)2048 * 4);        // [WQ_b, zeros]
  u16* QA    = (u16*)alloc((size_t)Mz * 2048 * 2);      // cols 0-1023: Q, 1024-2047: KA|VA
  u16* Kb    = (u16*)alloc((size_t)Mz * Dz * 2);
  u16* Vtg   = (u16*)alloc((size_t)Mz * Dz * 2);        // [bh][64][2048]
  u16* AOb   = hsb;                                     // attn out overwrites hs bf16

  // converts (weight concat: rows 0-1023=WQ, 1024-1535=WKA, 1536-2047=WVA)
  convert_bf16<<<(Mz * Dz) / 8 / 256, 256, 0, stream>>>(hs, hsb, Mz * Dz);
  convert_bf16<<<(Dz * Dz) / 8 / 256, 256, 0, stream>>>(WQ_w, wcat, Dz * Dz);
  convert_bf16<<<(Rz * Dz) / 8 / 256, 256, 0, stream>>>(WKA_w, wcat + (size_t)Dz * Dz, Rz * Dz);
  convert_bf16<<<(Rz * Dz) / 8 / 256, 256, 0, stream>>>(WVA_w, wcat + (size_t)1536 * Dz, Rz * Dz);
  convert_bf16<<<(Dz * Rz) / 8 / 256, 256, 0, stream>>>(WKB_w, wkbb, Dz * Rz);
  convert_bf16<<<(Dz * Rz) / 8 / 256, 256, 0, stream>>>(WVB_w, wvbb, Dz * Rz);
  transpose_convert<<<dim3(Dz / 32, Dz / 32), dim3(32, 8), 0, stream>>>(WC_w, wcb, Dz, Dz);
  make_biascat<<<8, 256, 0, stream>>>(WQ_b, bcat);

  // fused Q|KA|VA projection: QA[8192][2048] = hsb * wcat^T + bcat
  gemm_nt<0><<<dim3(2048 / 128, Mz / 128), 256, 0, stream>>>(hsb, wcat, bcat, QA,
                                                             Mz, 2048, Dz, Dz);
  // K = QA[:,1024:1536] * WK_B^T + b   (lda 2048)
  gemm_nt<0><<<dim3(Dz / 128, Mz / 128), 256, 0, stream>>>(QA + Dz, wkbb, WKB_b, Kb,
                                                           Mz, Dz, Rz, 2048);
  // V (written transposed): Vt[bh][d][s] = (QA[:,1536:2048] * WV_B^T + b)^T
  gemm_nt<2><<<dim3(Dz / 128, Mz / 128), 256, 0, stream>>>(QA + 1536, wvbb, WVB_b, Vtg,
                                                           Mz, Dz, Rz, 2048);

  // attention (Q from QA cols 0-1023, lda 2048); paired q-tiles, grid.x = 8
  attn_kernel<<<dim3(Sz / 256, Bz * Hz), 256, 0, stream>>>(QA, Kb, Vtg, AOb);

  // output projection -> f32
  gemm_nt<1><<<dim3(Dz / 128, Mz / 128), 256, 0, stream>>>(AOb, wcb, WC_b, out,
                                                           Mz, Dz, Dz, Dz);
}

// Round 7
// 282.031 us; speedup vs baseline: 1.5641x; 1.1039x over previous
//
#include <hip/hip_runtime.h>

// Problem constants
#define Bz 4
#define Sz 2048
#define Dz 1024
#define Hz 16
#define HDz 64
#define Rz 512
#define Mz (Bz * Sz)  // 8192 total rows

typedef unsigned short u16;
typedef __bf16 bf16x8 __attribute__((ext_vector_type(8)));
typedef __bf16 bf16x4 __attribute__((ext_vector_type(4)));
typedef float f32x4 __attribute__((ext_vector_type(4)));
typedef u16 u16x8 __attribute__((ext_vector_type(8)));
typedef u16 u16x4 __attribute__((ext_vector_type(4)));

__device__ __forceinline__ u16 f2bf(float f) {
  unsigned u = __builtin_bit_cast(unsigned, f);
  u += 0x7fffu + ((u >> 16) & 1u);  // RNE
  return (u16)(u >> 16);
}

#define GLDS(g, l)                                                              \
  __builtin_amdgcn_global_load_lds(                                             \
      (const __attribute__((address_space(1))) void*)(g),                       \
      (__attribute__((address_space(3))) void*)(l), 16, 0, 0)

// ---------------- f32 -> bf16 convert (n % 8 == 0) ----------------
__global__ void convert_bf16(const float* __restrict__ in, u16* __restrict__ out, int n) {
  int i = (blockIdx.x * blockDim.x + threadIdx.x) * 8;
  if (i >= n) return;
  float4 a = *(const float4*)(in + i);
  float4 b = *(const float4*)(in + i + 4);
  u16x8 r;
  r[0] = f2bf(a.x); r[1] = f2bf(a.y); r[2] = f2bf(a.z); r[3] = f2bf(a.w);
  r[4] = f2bf(b.x); r[5] = f2bf(b.y); r[6] = f2bf(b.z); r[7] = f2bf(b.w);
  *(u16x8*)(out + i) = r;
}

// ---------------- transpose + convert: out[C][R] = in[R][C]^T ----------------
__global__ void transpose_convert(const float* __restrict__ in, u16* __restrict__ out,
                                  int R, int C) {
  __shared__ float t[32][33];
  int bx = blockIdx.x * 32, by = blockIdx.y * 32;
  int x = threadIdx.x, y = threadIdx.y;  // block (32,8)
#pragma unroll
  for (int j = 0; j < 32; j += 8) t[y + j][x] = in[(size_t)(by + y + j) * C + bx + x];
  __syncthreads();
#pragma unroll
  for (int j = 0; j < 32; j += 8)
    out[(size_t)(bx + y + j) * R + by + x] = f2bf(t[x][y + j]);
}

// ---------------- concat bias: [WQ_b (1024), zeros (1024)] ----------------
__global__ void make_biascat(const float* __restrict__ qb_, float* __restrict__ out) {
  int i = blockIdx.x * 256 + threadIdx.x;  // 2048 total
  out[i] = (i < Dz) ? qb_[i] : 0.0f;
}

// ---------------- legacy NT GEMM (128x128, m97 structure) — c_proj only ---------
template <int MODE>  // 1: f32 row-major out
__global__ __launch_bounds__(256) void gemm_nt(const u16* __restrict__ A,
                                               const u16* __restrict__ W,
                                               const float* __restrict__ bias,
                                               void* __restrict__ Cv,
                                               int M, int N, int K, int lda) {
  __shared__ u16 As[128 * 32];
  __shared__ u16 Bs[128 * 32];
  const int tid = threadIdx.x;
  const int wid = tid >> 6, lane = tid & 63;
  const int nwg = gridDim.x * gridDim.y;
  const int id = blockIdx.y * gridDim.x + blockIdx.x;
  const int swz = (id & 7) * (nwg >> 3) + (id >> 3);
  const int bx = swz % gridDim.x, by = swz / gridDim.x;
  const int row0 = by * 128, col0 = bx * 128;
  const int wm = (wid >> 1) * 64, wn = (wid & 1) * 64;
  f32x4 acc[4][4] = {};
  const int srow = lane >> 2, scol = (lane & 3) * 8;
  const int frow = lane & 15, fk = (lane >> 4) * 8;

  for (int k0 = 0; k0 < K; k0 += 32) {
    __syncthreads();
#pragma unroll
    for (int it = 0; it < 2; ++it) {
      int c = it * 4 + wid;
      const u16* ga = A + (size_t)(row0 + c * 16 + srow) * lda + k0 + scol;
      const u16* gb = W + (size_t)(col0 + c * 16 + srow) * K + k0 + scol;
      GLDS(ga, As + c * 512);
      GLDS(gb, Bs + c * 512);
    }
    __syncthreads();
    bf16x8 af[4], bfr[4];
#pragma unroll
    for (int m = 0; m < 4; ++m) af[m] = *(const bf16x8*)(As + (wm + m * 16 + frow) * 32 + fk);
#pragma unroll
    for (int n = 0; n < 4; ++n) bfr[n] = *(const bf16x8*)(Bs + (wn + n * 16 + frow) * 32 + fk);
#pragma unroll
    for (int m = 0; m < 4; ++m)
#pragma unroll
      for (int n = 0; n < 4; ++n)
        acc[m][n] = __builtin_amdgcn_mfma_f32_16x16x32_bf16(af[m], bfr[n], acc[m][n], 0, 0, 0);
  }

  const int r4 = (lane >> 4) * 4, cc = lane & 15;
#pragma unroll
  for (int m = 0; m < 4; ++m)
#pragma unroll
    for (int n = 0; n < 4; ++n) {
      int col = col0 + wn + n * 16 + cc;
      float bv = bias[col];
#pragma unroll
      for (int j = 0; j < 4; ++j) {
        int row = row0 + wm + m * 16 + r4 + j;
        ((float*)Cv)[(size_t)row * N + col] = acc[m][n][j] + bv;
      }
    }
}

// ---------------- 256x256 BK=64 NT GEMM (8 waves, dbuf LDS, swizzled) ----------
// C[M=8192, N] = A[.,K](lda) * W[N,K]^T + bias. z-batched: blockIdx.z selects
// the {A,W,bias,C,mode} set (mode 0: bf16 row-major; mode 2: V-transposed
// Vt[bh][d][s]). LDS 128KB: 2 dbuf x (A 256x64 + B 256x64) bf16, XOR-swizzled
// byte ^= (row&7)<<4 via pre-swizzled global_load_lds source (rule #21) +
// swizzled ds_read — A/B frag reads 2-way conflict = free. One barrier per
// K-tile (stage next buf -> read cur -> MFMA -> sync; dbuf makes this safe).
__global__ __launch_bounds__(512, 2) void gemm256(
    const u16* __restrict__ A0, const u16* __restrict__ W0,
    const float* __restrict__ bias0, void* __restrict__ C0, int mode0,
    const u16* __restrict__ A1, const u16* __restrict__ W1,
    const float* __restrict__ bias1, void* __restrict__ C1, int mode1,
    int N, int K, int lda) {
  __shared__ __align__(16) u16 As[2][256 * 64];
  __shared__ __align__(16) u16 Bs[2][256 * 64];
  const int z = blockIdx.z;
  const u16* A = z ? A1 : A0;
  const u16* W = z ? W1 : W0;
  const float* bias = z ? bias1 : bias0;
  void* Cv = z ? C1 : C0;
  const int mode = z ? mode1 : mode0;

  const int tid = threadIdx.x, wid = tid >> 6, lane = tid & 63;
  const int gx = gridDim.x;
  const int nwg = gx * gridDim.y;
  const int id = blockIdx.y * gx + blockIdx.x;
  const int swz = (id & 7) * (nwg >> 3) + (id >> 3);
  const int bx = swz % gx, by = swz / gx;
  const int row0 = by * 256, col0 = bx * 256;
  const int wr = wid >> 2, wc = wid & 3;  // wave 2x4 grid; per-wave out 128x64
  const int frow = lane & 15, fhi = lane >> 4;

  // staging geometry: 4 rounds x 512 threads x 16B cover a 32KB tile.
  // phys byte P = rnd*8192 + tid*16 (linear DMA dest); global src supplies the
  // element whose swizzled addr == P: logical L = P ^ ((P>>7 & 7)<<4).
  const u16* ap[4];
  const u16* bp[4];
#pragma unroll
  for (int rnd = 0; rnd < 4; ++rnd) {
    int P = rnd * 8192 + tid * 16;
    int L = P ^ (((P >> 7) & 7) << 4);
    int r = L >> 7, c = (L & 127) >> 1;
    ap[rnd] = A + (size_t)(row0 + r) * lda + c;
    bp[rnd] = W + (size_t)(col0 + r) * K + c;
  }

  auto stage = [&](int buf, int kt) {
    const int k0 = kt * 64;
#pragma unroll
    for (int rnd = 0; rnd < 4; ++rnd) {
      GLDS(ap[rnd] + k0, &As[buf][rnd * 4096 + tid * 8]);
      GLDS(bp[rnd] + k0, &Bs[buf][rnd * 4096 + tid * 8]);
    }
  };
  // swizzled LDS fragment read: logical (row, byte-col) -> phys
  auto rd = [](const u16* base, int row, int colb) -> bf16x8 {
    int off = ((row << 7) + colb) ^ ((row & 7) << 4);
    return *(const bf16x8*)((const char*)base + off);
  };

  f32x4 acc[8][4] = {};
  const int NT = K >> 6;
  stage(0, 0);
  __syncthreads();
  int cur = 0;
  for (int kt = 0; kt < NT; ++kt) {
    if (kt + 1 < NT) stage(cur ^ 1, kt + 1);  // T14: issue into other buf now
    bf16x8 bfr[2][4];
#pragma unroll
    for (int ks = 0; ks < 2; ++ks)
#pragma unroll
      for (int n = 0; n < 4; ++n)
        bfr[ks][n] = rd(Bs[cur], wc * 64 + n * 16 + frow, ks * 64 + fhi * 16);
    __builtin_amdgcn_s_setprio(1);
#pragma unroll
    for (int mg = 0; mg < 4; ++mg) {
      bf16x8 af[2][2];
#pragma unroll
      for (int mi = 0; mi < 2; ++mi)
#pragma unroll
        for (int ks = 0; ks < 2; ++ks)
          af[mi][ks] = rd(As[cur], wr * 128 + mg * 32 + mi * 16 + frow, ks * 64 + fhi * 16);
#pragma unroll
      for (int mi = 0; mi < 2; ++mi)
#pragma unroll
        for (int ks = 0; ks < 2; ++ks)
#pragma unroll
          for (int n = 0; n < 4; ++n)
            acc[mg * 2 + mi][n] = __builtin_amdgcn_mfma_f32_16x16x32_bf16(
                af[mi][ks], bfr[ks][n], acc[mg * 2 + mi][n], 0, 0, 0);
    }
    __builtin_amdgcn_s_setprio(0);
    __syncthreads();  // all waves: reads of cur done, stages into cur^1 landed
    cur ^= 1;
  }

  // epilogue: C/D frag col=frow, row=fhi*4+j
#pragma unroll
  for (int m = 0; m < 8; ++m)
#pragma unroll
    for (int n = 0; n < 4; ++n) {
      const int col = col0 + wc * 64 + n * 16 + frow;
      const int rowb = row0 + wr * 128 + m * 16 + fhi * 4;
      const float bv = bias[col];
      if (mode == 2) {
        size_t obase = (size_t)((rowb >> 11) * Hz + (col >> 6)) * ((size_t)HDz * Sz) +
                       (size_t)(col & 63) * Sz + (rowb & 2047);
        u16x4 w4;
#pragma unroll
        for (int j = 0; j < 4; ++j) w4[j] = f2bf(acc[m][n][j] + bv);
        *(u16x4*)((u16*)Cv + obase) = w4;
      } else {
#pragma unroll
        for (int j = 0; j < 4; ++j)
          ((u16*)Cv)[(size_t)(rowb + j) * N + col] = f2bf(acc[m][n][j] + bv);
      }
    }
}

// swizzled LDS address: row-major [*][64] u16 (128B rows), byte ^= (row&7)<<4
__device__ __forceinline__ void* lsw(void* base, int row, int bo) {
  return (char*)base + (((row << 7) + bo) ^ ((row & 7) << 4));
}

// one q-tile x k-tile step: QK^T (swapped), static-max softmax, PV (swapped).
// MASK: compile-time diagonal specialization (koff = k-offset within q-tile).
template <bool MASK>
__device__ __forceinline__ void tile_step(u16* Ks, u16* Vts, u16* Pw,
                                          int frow, int fhi, int qlocb, int koff,
                                          const bf16x8 (&qf)[2][2],
                                          f32x4 (&o)[4][2], float* rs) {
#pragma unroll
  for (int qs = 0; qs < 2; ++qs) {
    f32x4 s[4] = {};
#pragma unroll
    for (int dc = 0; dc < 2; ++dc)
#pragma unroll
      for (int c = 0; c < 4; ++c) {
        bf16x8 kf = *(const bf16x8*)lsw(Ks, c * 16 + frow, dc * 64 + fhi * 16);
        s[c] = __builtin_amdgcn_mfma_f32_16x16x32_bf16(kf, qf[qs][dc], s[c], 0, 0, 0);
      }
    const int qloc = qlocb + qs * 16 + frow;
#pragma unroll
    for (int c = 0; c < 4; ++c) {
      bf16x4 w;
#pragma unroll
      for (int j = 0; j < 4; ++j) {
        float v = __builtin_exp2f(s[c][j] * 0.18033688f);  // fold 1/8 * log2(e)
        if (MASK) v = ((koff + c * 16 + fhi * 4 + j) <= qloc) ? v : 0.0f;
        rs[qs] += v;
        w[j] = (__bf16)v;  // compiler -> v_cvt_pk_bf16_f32
      }
      *(bf16x4*)lsw(Pw, qs * 16 + frow, c * 32 + fhi * 8) = w;
    }
  }
#pragma unroll
  for (int kc = 0; kc < 2; ++kc) {
    bf16x8 pa0 = *(const bf16x8*)lsw(Pw, frow, kc * 64 + fhi * 16);
    bf16x8 pa1 = *(const bf16x8*)lsw(Pw, 16 + frow, kc * 64 + fhi * 16);
#pragma unroll
    for (int n = 0; n < 4; ++n) {
      bf16x8 vf = *(const bf16x8*)lsw(Vts, n * 16 + frow, kc * 64 + fhi * 16);
      o[n][0] = __builtin_amdgcn_mfma_f32_16x16x32_bf16(vf, pa0, o[n][0], 0, 0, 0);
      o[n][1] = __builtin_amdgcn_mfma_f32_16x16x32_bf16(vf, pa1, o[n][1], 0, 0, 0);
    }
  }
}

// ---------------- causal flash attention (v4: paired q-tiles) ----------------
// grid: (8, B*H). Block p handles q-tiles qA=p (light) and qB=15-p (heavy):
// per-block compute = (2p+2)+(32-2p) = 34 q-k-tiles, UNIFORM across blocks.
// 512 blocks = exactly 2/CU resident start-to-finish.
__global__ __launch_bounds__(256, 2) void attn_kernel(const u16* __restrict__ Q,
                                                      const u16* __restrict__ Kg,
                                                      const u16* __restrict__ Vt,
                                                      u16* __restrict__ Og) {
  __shared__ __align__(16) u16 Ks[64 * 64];
  __shared__ __align__(16) u16 Vts[64 * 64];
  __shared__ __align__(16) u16 Ps[4][32 * 64];
  const int pr = blockIdx.x;               // 0..7
  const int qA = pr, qB = 15 - pr;         // light, heavy q-tile indices
  const int bh = blockIdx.y;
  const int tid = threadIdx.x, wid = tid >> 6, lane = tid & 63;
  const size_t kbase = (size_t)(bh >> 4) * Sz * Dz + (size_t)(bh & 15) * HDz;
  const size_t qbase = (size_t)(bh >> 4) * Sz * 2048 + (size_t)(bh & 15) * HDz;  // Q lda=2048
  const size_t vtb = (size_t)bh * HDz * Sz;
  const int frow = lane & 15, fhi = lane >> 4;
  const int q0A = qA * 128 + wid * 32, q0B = qB * 128 + wid * 32;

  bf16x8 qfA[2][2], qfB[2][2];
#pragma unroll
  for (int qs = 0; qs < 2; ++qs)
#pragma unroll
    for (int dc = 0; dc < 2; ++dc) {
      qfA[qs][dc] = *(const bf16x8*)(Q + qbase + (size_t)(q0A + qs * 16 + frow) * 2048 +
                                     dc * 32 + fhi * 8);
      qfB[qs][dc] = *(const bf16x8*)(Q + qbase + (size_t)(q0B + qs * 16 + frow) * 2048 +
                                     dc * 32 + fhi * 8);
    }

  f32x4 oA[4][2] = {}, oB[4][2] = {};
  float rsA[2] = {0.0f, 0.0f}, rsB[2] = {0.0f, 0.0f};

  // staging: thread covers row r, bytes [cb, cb+32)
  const int r = tid >> 2, cb = (tid & 3) * 32;
  const u16* kgp = Kg + kbase + (size_t)r * Dz + (tid & 3) * 16;
  const u16* vgp = Vt + vtb + (size_t)r * Sz + (tid & 3) * 16;

  const int ntB = 2 * qB + 2;
  u16x8 ka = *(const u16x8*)(kgp);
  u16x8 kb2 = *(const u16x8*)(kgp + 8);
  u16x8 va = *(const u16x8*)(vgp);
  u16x8 vb2 = *(const u16x8*)(vgp + 8);

  for (int t = 0; t < ntB; ++t) {
    __syncthreads();  // previous tile's LDS reads done
    *(u16x8*)lsw(Ks, r, cb) = ka;
    *(u16x8*)lsw(Ks, r, cb + 16) = kb2;
    *(u16x8*)lsw(Vts, r, cb) = va;
    *(u16x8*)lsw(Vts, r, cb + 16) = vb2;
    if (t + 1 < ntB) {  // T14: issue next-tile loads now, land during compute
      const size_t ko = (size_t)(t + 1) * 64 * Dz;
      const size_t vo = (size_t)(t + 1) * 64;
      ka = *(const u16x8*)(kgp + ko);
      kb2 = *(const u16x8*)(kgp + ko + 8);
      va = *(const u16x8*)(vgp + vo);
      vb2 = *(const u16x8*)(vgp + vo + 8);
    }
    __syncthreads();  // LDS ready

    // heavy tile B (active for all t up to its diagonal)
    if (64 * t <= q0B + 31) {
      if (t >= 2 * qB)
        tile_step<true>(Ks, Vts, Ps[wid], frow, fhi, wid * 32, (t - 2 * qB) * 64,
                        qfB, oB, rsB);
      else
        tile_step<false>(Ks, Vts, Ps[wid], frow, fhi, wid * 32, 0, qfB, oB, rsB);
    }
    // light tile A (active only for t <= 2*qA+1)
    if (64 * t <= q0A + 31) {
      if (t >= 2 * qA)
        tile_step<true>(Ks, Vts, Ps[wid], frow, fhi, wid * 32, (t - 2 * qA) * 64,
                        qfA, oA, rsA);
      else
        tile_step<false>(Ks, Vts, Ps[wid], frow, fhi, wid * 32, 0, qfA, oA, rsA);
    }
  }

  // epilogue: denom for q = q0+qs*16+frow lives on this lane after fhi-reduce
#pragma unroll
  for (int x = 0; x < 2; ++x) {
    f32x4(&o)[4][2] = x ? oA : oB;
    float* rs = x ? rsA : rsB;
    const int q0 = x ? q0A : q0B;
#pragma unroll
    for (int qs = 0; qs < 2; ++qs) {
      float l = rs[qs];
      l += __shfl_xor(l, 16);
      l += __shfl_xor(l, 32);
      float inv = 1.0f / l;
      const size_t ob = kbase + (size_t)(q0 + qs * 16 + frow) * Dz;
#pragma unroll
      for (int n = 0; n < 4; ++n) {
        bf16x4 w;
#pragma unroll
        for (int j = 0; j < 4; ++j) w[j] = (__bf16)(o[n][qs][j] * inv);
        *(bf16x4*)(Og + ob + n * 16 + fhi * 4) = w;
      }
    }
  }
}

// ---------------- host launcher ----------------
extern "C" void kernel_launch(void* const* d_in, const int* in_sizes, int n_in,
                              void* d_out, int out_size, void* d_ws, size_t ws_size,
                              hipStream_t stream) {
  const float* hs    = (const float*)d_in[0];
  const float* WQ_w  = (const float*)d_in[1];
  const float* WQ_b  = (const float*)d_in[2];
  const float* WKA_w = (const float*)d_in[3];
  const float* WKB_w = (const float*)d_in[4];
  const float* WKB_b = (const float*)d_in[5];
  const float* WVA_w = (const float*)d_in[6];
  const float* WVB_w = (const float*)d_in[7];
  const float* WVB_b = (const float*)d_in[8];
  const float* WC_w  = (const float*)d_in[9];
  const float* WC_b  = (const float*)d_in[10];
  float* out = (float*)d_out;

  char* p = (char*)d_ws;
  auto alloc = [&](size_t bytes) {
    char* r = p;
    p += (bytes + 255) & ~(size_t)255;
    return r;
  };
  u16* hsb   = (u16*)alloc((size_t)Mz * Dz * 2);        // hs bf16; reused as attn out
  u16* wcat  = (u16*)alloc((size_t)2048 * Dz * 2);      // [WQ; WKA; WVA] rows
  u16* wkbb  = (u16*)alloc((size_t)Dz * Rz * 2);
  u16* wvbb  = (u16*)alloc((size_t)Dz * Rz * 2);
  u16* wcb   = (u16*)alloc((size_t)Dz * Dz * 2);        // c_proj_w transposed
  float* bcat = (float*)alloc((size_t)2048 * 4);        // [WQ_b, zeros]
  u16* QA    = (u16*)alloc((size_t)Mz * 2048 * 2);      // cols 0-1023: Q, 1024-2047: KA|VA
  u16* Kb    = (u16*)alloc((size_t)Mz * Dz * 2);
  u16* Vtg   = (u16*)alloc((size_t)Mz * Dz * 2);        // [bh][64][2048]
  u16* AOb   = hsb;                                     // attn out overwrites hs bf16

  // converts (weight concat: rows 0-1023=WQ, 1024-1535=WKA, 1536-2047=WVA)
  convert_bf16<<<(Mz * Dz) / 8 / 256, 256, 0, stream>>>(hs, hsb, Mz * Dz);
  convert_bf16<<<(Dz * Dz) / 8 / 256, 256, 0, stream>>>(WQ_w, wcat, Dz * Dz);
  convert_bf16<<<(Rz * Dz) / 8 / 256, 256, 0, stream>>>(WKA_w, wcat + (size_t)Dz * Dz, Rz * Dz);
  convert_bf16<<<(Rz * Dz) / 8 / 256, 256, 0, stream>>>(WVA_w, wcat + (size_t)1536 * Dz, Rz * Dz);
  convert_bf16<<<(Dz * Rz) / 8 / 256, 256, 0, stream>>>(WKB_w, wkbb, Dz * Rz);
  convert_bf16<<<(Dz * Rz) / 8 / 256, 256, 0, stream>>>(WVB_w, wvbb, Dz * Rz);
  transpose_convert<<<dim3(Dz / 32, Dz / 32), dim3(32, 8), 0, stream>>>(WC_w, wcb, Dz, Dz);
  make_biascat<<<8, 256, 0, stream>>>(WQ_b, bcat);

  // fused Q|KA|VA projection: QA[8192][2048] = hsb * wcat^T + bcat  (256² kernel)
  gemm256<<<dim3(2048 / 256, Mz / 256, 1), 512, 0, stream>>>(
      hsb, wcat, bcat, QA, 0, hsb, wcat, bcat, QA, 0, 2048, Dz, Dz);

  // z-batched K and V GEMMs (K: bf16 row-major; V: written transposed)
  gemm256<<<dim3(Dz / 256, Mz / 256, 2), 512, 0, stream>>>(
      QA + Dz, wkbb, WKB_b, Kb, 0,
      QA + 1536, wvbb, WVB_b, Vtg, 2, Dz, Rz, 2048);

  // attention (Q from QA cols 0-1023, lda 2048); paired q-tiles, grid.x = 8
  attn_kernel<<<dim3(Sz / 256, Bz * Hz), 256, 0, stream>>>(QA, Kb, Vtg, AOb);

  // output projection -> f32 (legacy 128² kernel: 512 blocks = full machine)
  gemm_nt<1><<<dim3(Dz / 128, Mz / 128), 256, 0, stream>>>(AOb, wcb, WC_b, out,
                                                           Mz, Dz, Dz, Dz);
}

// Round 9
// 279.210 us; speedup vs baseline: 1.5799x; 1.0101x over previous
//
#include <hip/hip_runtime.h>

// Problem constants
#define Bz 4
#define Sz 2048
#define Dz 1024
#define Hz 16
#define HDz 64
#define Rz 512
#define Mz (Bz * Sz)  // 8192 total rows

typedef unsigned short u16;
typedef __bf16 bf16x8 __attribute__((ext_vector_type(8)));
typedef __bf16 bf16x4 __attribute__((ext_vector_type(4)));
typedef float f32x4 __attribute__((ext_vector_type(4)));
typedef u16 u16x8 __attribute__((ext_vector_type(8)));
typedef u16 u16x4 __attribute__((ext_vector_type(4)));

__device__ __forceinline__ u16 f2bf(float f) {
  unsigned u = __builtin_bit_cast(unsigned, f);
  u += 0x7fffu + ((u >> 16) & 1u);  // RNE
  return (u16)(u >> 16);
}

#define GLDS(g, l)                                                              \
  __builtin_amdgcn_global_load_lds(                                             \
      (const __attribute__((address_space(1))) void*)(g),                       \
      (__attribute__((address_space(3))) void*)(l), 16, 0, 0)

// ---------------- f32 -> bf16 convert with scale (n % 8 == 0) ----------------
__global__ void convert_bf16(const float* __restrict__ in, u16* __restrict__ out,
                             int n, float scale) {
  int i = (blockIdx.x * blockDim.x + threadIdx.x) * 8;
  if (i >= n) return;
  float4 a = *(const float4*)(in + i);
  float4 b = *(const float4*)(in + i + 4);
  u16x8 r;
  r[0] = f2bf(a.x * scale); r[1] = f2bf(a.y * scale);
  r[2] = f2bf(a.z * scale); r[3] = f2bf(a.w * scale);
  r[4] = f2bf(b.x * scale); r[5] = f2bf(b.y * scale);
  r[6] = f2bf(b.z * scale); r[7] = f2bf(b.w * scale);
  *(u16x8*)(out + i) = r;
}

// ---------------- transpose + convert: out[C][R] = in[R][C]^T ----------------
__global__ void transpose_convert(const float* __restrict__ in, u16* __restrict__ out,
                                  int R, int C) {
  __shared__ float t[32][33];
  int bx = blockIdx.x * 32, by = blockIdx.y * 32;
  int x = threadIdx.x, y = threadIdx.y;  // block (32,8)
#pragma unroll
  for (int j = 0; j < 32; j += 8) t[y + j][x] = in[(size_t)(by + y + j) * C + bx + x];
  __syncthreads();
#pragma unroll
  for (int j = 0; j < 32; j += 8)
    out[(size_t)(bx + y + j) * R + by + x] = f2bf(t[x][y + j]);
}

// ---------------- concat bias: [WQ_b * softmax-scale (1024), zeros (1024)] ----
__global__ void make_biascat(const float* __restrict__ qb_, float* __restrict__ out) {
  int i = blockIdx.x * 256 + threadIdx.x;  // 2048 total
  out[i] = (i < Dz) ? qb_[i] * 0.18033688f : 0.0f;
}

// ---------------- counted-vmcnt NT GEMM (BMx256, BK-half=32 pipeline) ----------
// C = A[.,K](lda) * W[N,K]^T + bias. z-batched param sets. T3+T4: 4 rotating
// 16KB LDS regions per operand, depth-3 half-tile prefetch, s_waitcnt vmcnt(8/6)
// + raw s_barrier per step — loads never drain in the main loop (regions
// {h..h+3} mod 4 distinct; 3-iter tail peeled with vmcnt(0)).
// Region layout [rows][32]u16 (64B rows), cross-row XOR swizzle
// P = L ^ ((L>>2)&0x70) (bijective unipotent map; frag reads 2-way = free);
// inverse applied to the global_load_lds SOURCE (rule #21).
// Hardening (rule #18): lgkmcnt(0) fence at body entry (prev iter's ds_reads
// drained before crossing the barrier; never actually stalls — reads complete
// under MFMA latency) + sched_barrier(0) after s_barrier (pin read cluster).
// mode 0: bf16 row-major; 1: f32 row-major; 2: bf16 V-transposed Vt[bh][d][s].
template <int BM>
__global__ __launch_bounds__(512, 2) void gemm256(
    const u16* __restrict__ A0, const u16* __restrict__ W0,
    const float* __restrict__ bias0, void* __restrict__ C0, int mode0,
    const u16* __restrict__ A1, const u16* __restrict__ W1,
    const float* __restrict__ bias1, void* __restrict__ C1, int mode1,
    int N, int K, int lda) {
  constexpr int MF = BM / 32;      // m-frags per wave (wave rows = BM/2)
  constexpr int ARND = BM / 128;   // GLDS rounds per A half-region
  __shared__ __align__(16) u16 As[4][BM * 32];
  __shared__ __align__(16) u16 Bs[4][256 * 32];

  const int z = blockIdx.z;
  const u16* A = z ? A1 : A0;
  const u16* W = z ? W1 : W0;
  const float* bias = z ? bias1 : bias0;
  void* Cv = z ? C1 : C0;
  const int mode = z ? mode1 : mode0;

  const int tid = threadIdx.x, wid = tid >> 6, lane = tid & 63;
  const int gx = gridDim.x;
  const int nwg = gx * gridDim.y;
  const int id = blockIdx.y * gx + blockIdx.x;
  const int swz = (id & 7) * (nwg >> 3) + (id >> 3);
  const int bx = swz % gx, by = swz / gx;
  const int row0 = by * BM, col0 = bx * 256;
  const int wr = wid >> 2, wc = wid & 3;  // wave 2x4 grid
  const int frow = lane & 15, fhi = lane >> 4;

  // staging source pointers (inverse-swizzled). P = rnd*8192 + tid*16.
  const u16* ap[ARND];
  const u16* bp[2];
#pragma unroll
  for (int rnd = 0; rnd < 2; ++rnd) {
    int P = rnd * 8192 + tid * 16;
    int l6 = ((P >> 6) ^ (P >> 8)) & 1;
    int l5 = ((P >> 5) ^ (P >> 7)) & 1;
    int l4 = ((P >> 4) & 1) ^ l6;
    int L = (P & ~0x70) | (l6 << 6) | (l5 << 5) | (l4 << 4);
    int row = L >> 6, colu = (L & 63) >> 1;
    if (rnd < ARND) ap[rnd] = A + (size_t)(row0 + row) * lda + colu;
    bp[rnd] = W + (size_t)(col0 + row) * K + colu;
  }

  const int H = K >> 5;  // number of 32-k halves
  auto stage = [&](int h) {
    const int off = h * 32;
    const int slot = h & 3;
#pragma unroll
    for (int rnd = 0; rnd < ARND; ++rnd)
      GLDS(ap[rnd] + off, &As[slot][rnd * 4096 + tid * 8]);
#pragma unroll
    for (int rnd = 0; rnd < 2; ++rnd)
      GLDS(bp[rnd] + off, &Bs[slot][rnd * 4096 + tid * 8]);
  };
  // swizzled frag read from a region
  auto rd = [](const u16* base, int row, int bo) -> bf16x8 {
    int L = (row << 6) + bo;
    int P = L ^ ((L >> 2) & 0x70);
    return *(const bf16x8*)((const char*)base + P);
  };

  f32x4 acc[MF][4] = {};

  stage(0); stage(1); stage(2);

  auto body = [&](int h, bool mainphase) {
    // drain prev iter's ds_reads before crossing the barrier (rule #18 guard)
    asm volatile("s_waitcnt lgkmcnt(0)" ::: "memory");
    if (mainphase) {
      if constexpr (BM == 256)
        asm volatile("s_waitcnt vmcnt(8)" ::: "memory");
      else
        asm volatile("s_waitcnt vmcnt(6)" ::: "memory");
    } else {
      asm volatile("s_waitcnt vmcnt(0)" ::: "memory");
    }
    __builtin_amdgcn_s_barrier();
    __builtin_amdgcn_sched_barrier(0);  // pin: no ds_read hoists above barrier
    const int slot = h & 3;
    bf16x8 bfr[4];
#pragma unroll
    for (int n = 0; n < 4; ++n)
      bfr[n] = rd(Bs[slot], wc * 64 + n * 16 + frow, fhi * 16);
    bf16x8 af[MF];
#pragma unroll
    for (int m = 0; m < MF; ++m)
      af[m] = rd(As[slot], wr * (BM / 2) + m * 16 + frow, fhi * 16);
    if (mainphase) stage(h + 3);
    __builtin_amdgcn_s_setprio(1);
#pragma unroll
    for (int m = 0; m < MF; ++m)
#pragma unroll
      for (int n = 0; n < 4; ++n)
        acc[m][n] = __builtin_amdgcn_mfma_f32_16x16x32_bf16(af[m], bfr[n], acc[m][n], 0, 0, 0);
    __builtin_amdgcn_s_setprio(0);
  };

  for (int h = 0; h < H - 3; ++h) body(h, true);
  for (int h = H - 3; h < H; ++h) body(h, false);

  // epilogue: C/D frag col=frow, row=fhi*4+j
#pragma unroll
  for (int m = 0; m < MF; ++m)
#pragma unroll
    for (int n = 0; n < 4; ++n) {
      const int col = col0 + wc * 64 + n * 16 + frow;
      const int rowb = row0 + wr * (BM / 2) + m * 16 + fhi * 4;
      const float bv = bias[col];
      if (mode == 2) {
        size_t obase = (size_t)((rowb >> 11) * Hz + (col >> 6)) * ((size_t)HDz * Sz) +
                       (size_t)(col & 63) * Sz + (rowb & 2047);
        u16x4 w4;
#pragma unroll
        for (int j = 0; j < 4; ++j) w4[j] = f2bf(acc[m][n][j] + bv);
        *(u16x4*)((u16*)Cv + obase) = w4;
      } else if (mode == 1) {
#pragma unroll
        for (int j = 0; j < 4; ++j)
          ((float*)Cv)[(size_t)(rowb + j) * N + col] = acc[m][n][j] + bv;
      } else {
#pragma unroll
        for (int j = 0; j < 4; ++j)
          ((u16*)Cv)[(size_t)(rowb + j) * N + col] = f2bf(acc[m][n][j] + bv);
      }
    }
}

// swizzled LDS address: row-major [*][64] u16 (128B rows), byte ^= (row&7)<<4
__device__ __forceinline__ void* lsw(void* base, int row, int bo) {
  return (char*)base + (((row << 7) + bo) ^ ((row & 7) << 4));
}

// one q-tile x k-tile step: QK^T (swapped), static-max softmax, PV (swapped).
// MASK: compile-time diagonal specialization (koff = k-offset within q-tile).
// Softmax scale pre-folded into WQ/WQ_b (Q' = Q * log2(e)/8) -> exp2(s) direct.
template <bool MASK>
__device__ __forceinline__ void tile_step(u16* Ks, u16* Vts, u16* Pw,
                                          int frow, int fhi, int qlocb, int koff,
                                          const bf16x8 (&qf)[2][2],
                                          f32x4 (&o)[4][2], float* rs) {
#pragma unroll
  for (int qs = 0; qs < 2; ++qs) {
    f32x4 s[4] = {};
#pragma unroll
    for (int dc = 0; dc < 2; ++dc)
#pragma unroll
      for (int c = 0; c < 4; ++c) {
        bf16x8 kf = *(const bf16x8*)lsw(Ks, c * 16 + frow, dc * 64 + fhi * 16);
        s[c] = __builtin_amdgcn_mfma_f32_16x16x32_bf16(kf, qf[qs][dc], s[c], 0, 0, 0);
      }
    const int qloc = qlocb + qs * 16 + frow;
#pragma unroll
    for (int c = 0; c < 4; ++c) {
      bf16x4 w;
#pragma unroll
      for (int j = 0; j < 4; ++j) {
        float v = __builtin_exp2f(s[c][j]);
        if (MASK) v = ((koff + c * 16 + fhi * 4 + j) <= qloc) ? v : 0.0f;
        rs[qs] += v;
        w[j] = (__bf16)v;  // compiler -> v_cvt_pk_bf16_f32
      }
      *(bf16x4*)lsw(Pw, qs * 16 + frow, c * 32 + fhi * 8) = w;
    }
  }
#pragma unroll
  for (int kc = 0; kc < 2; ++kc) {
    bf16x8 pa0 = *(const bf16x8*)lsw(Pw, frow, kc * 64 + fhi * 16);
    bf16x8 pa1 = *(const bf16x8*)lsw(Pw, 16 + frow, kc * 64 + fhi * 16);
#pragma unroll
    for (int n = 0; n < 4; ++n) {
      bf16x8 vf = *(const bf16x8*)lsw(Vts, n * 16 + frow, kc * 64 + fhi * 16);
      o[n][0] = __builtin_amdgcn_mfma_f32_16x16x32_bf16(vf, pa0, o[n][0], 0, 0, 0);
      o[n][1] = __builtin_amdgcn_mfma_f32_16x16x32_bf16(vf, pa1, o[n][1], 0, 0, 0);
    }
  }
}

// ---------------- causal flash attention (v4: paired q-tiles) ----------------
// grid: (8, B*H). Block p handles q-tiles qA=p (light) and qB=15-p (heavy):
// per-block compute = (2p+2)+(32-2p) = 34 q-k-tiles, UNIFORM across blocks.
// 512 blocks = exactly 2/CU resident start-to-finish.
__global__ __launch_bounds__(256, 2) void attn_kernel(const u16* __restrict__ Q,
                                                      const u16* __restrict__ Kg,
                                                      const u16* __restrict__ Vt,
                                                      u16* __restrict__ Og) {
  __shared__ __align__(16) u16 Ks[64 * 64];
  __shared__ __align__(16) u16 Vts[64 * 64];
  __shared__ __align__(16) u16 Ps[4][32 * 64];
  const int pr = blockIdx.x;               // 0..7
  const int qA = pr, qB = 15 - pr;         // light, heavy q-tile indices
  const int bh = blockIdx.y;
  const int tid = threadIdx.x, wid = tid >> 6, lane = tid & 63;
  const size_t kbase = (size_t)(bh >> 4) * Sz * Dz + (size_t)(bh & 15) * HDz;
  const size_t qbase = (size_t)(bh >> 4) * Sz * 2048 + (size_t)(bh & 15) * HDz;  // Q lda=2048
  const size_t vtb = (size_t)bh * HDz * Sz;
  const int frow = lane & 15, fhi = lane >> 4;
  const int q0A = qA * 128 + wid * 32, q0B = qB * 128 + wid * 32;

  bf16x8 qfA[2][2], qfB[2][2];
#pragma unroll
  for (int qs = 0; qs < 2; ++qs)
#pragma unroll
    for (int dc = 0; dc < 2; ++dc) {
      qfA[qs][dc] = *(const bf16x8*)(Q + qbase + (size_t)(q0A + qs * 16 + frow) * 2048 +
                                     dc * 32 + fhi * 8);
      qfB[qs][dc] = *(const bf16x8*)(Q + qbase + (size_t)(q0B + qs * 16 + frow) * 2048 +
                                     dc * 32 + fhi * 8);
    }

  f32x4 oA[4][2] = {}, oB[4][2] = {};
  float rsA[2] = {0.0f, 0.0f}, rsB[2] = {0.0f, 0.0f};

  // staging: thread covers row r, bytes [cb, cb+32)
  const int r = tid >> 2, cb = (tid & 3) * 32;
  const u16* kgp = Kg + kbase + (size_t)r * Dz + (tid & 3) * 16;
  const u16* vgp = Vt + vtb + (size_t)r * Sz + (tid & 3) * 16;

  const int ntB = 2 * qB + 2;
  u16x8 ka = *(const u16x8*)(kgp);
  u16x8 kb2 = *(const u16x8*)(kgp + 8);
  u16x8 va = *(const u16x8*)(vgp);
  u16x8 vb2 = *(const u16x8*)(vgp + 8);

  for (int t = 0; t < ntB; ++t) {
    __syncthreads();  // previous tile's LDS reads done
    *(u16x8*)lsw(Ks, r, cb) = ka;
    *(u16x8*)lsw(Ks, r, cb + 16) = kb2;
    *(u16x8*)lsw(Vts, r, cb) = va;
    *(u16x8*)lsw(Vts, r, cb + 16) = vb2;
    if (t + 1 < ntB) {  // T14: issue next-tile loads now, land during compute
      const size_t ko = (size_t)(t + 1) * 64 * Dz;
      const size_t vo = (size_t)(t + 1) * 64;
      ka = *(const u16x8*)(kgp + ko);
      kb2 = *(const u16x8*)(kgp + ko + 8);
      va = *(const u16x8*)(vgp + vo);
      vb2 = *(const u16x8*)(vgp + vo + 8);
    }
    __syncthreads();  // LDS ready

    // heavy tile B (active for all t up to its diagonal)
    if (64 * t <= q0B + 31) {
      if (t >= 2 * qB)
        tile_step<true>(Ks, Vts, Ps[wid], frow, fhi, wid * 32, (t - 2 * qB) * 64,
                        qfB, oB, rsB);
      else
        tile_step<false>(Ks, Vts, Ps[wid], frow, fhi, wid * 32, 0, qfB, oB, rsB);
    }
    // light tile A (active only for t <= 2*qA+1)
    if (64 * t <= q0A + 31) {
      if (t >= 2 * qA)
        tile_step<true>(Ks, Vts, Ps[wid], frow, fhi, wid * 32, (t - 2 * qA) * 64,
                        qfA, oA, rsA);
      else
        tile_step<false>(Ks, Vts, Ps[wid], frow, fhi, wid * 32, 0, qfA, oA, rsA);
    }
  }

  // epilogue: denom for q = q0+qs*16+frow lives on this lane after fhi-reduce
#pragma unroll
  for (int x = 0; x < 2; ++x) {
    f32x4(&o)[4][2] = x ? oA : oB;
    float* rs = x ? rsA : rsB;
    const int q0 = x ? q0A : q0B;
#pragma unroll
    for (int qs = 0; qs < 2; ++qs) {
      float l = rs[qs];
      l += __shfl_xor(l, 16);
      l += __shfl_xor(l, 32);
      float inv = 1.0f / l;
      const size_t ob = kbase + (size_t)(q0 + qs * 16 + frow) * Dz;
#pragma unroll
      for (int n = 0; n < 4; ++n) {
        bf16x4 w;
#pragma unroll
        for (int j = 0; j < 4; ++j) w[j] = (__bf16)(o[n][qs][j] * inv);
        *(bf16x4*)(Og + ob + n * 16 + fhi * 4) = w;
      }
    }
  }
}

// ---------------- host launcher ----------------
extern "C" void kernel_launch(void* const* d_in, const int* in_sizes, int n_in,
                              void* d_out, int out_size, void* d_ws, size_t ws_size,
                              hipStream_t stream) {
  const float* hs    = (const float*)d_in[0];
  const float* WQ_w  = (const float*)d_in[1];
  const float* WQ_b  = (const float*)d_in[2];
  const float* WKA_w = (const float*)d_in[3];
  const float* WKB_w = (const float*)d_in[4];
  const float* WKB_b = (const float*)d_in[5];
  const float* WVA_w = (const float*)d_in[6];
  const float* WVB_w = (const float*)d_in[7];
  const float* WVB_b = (const float*)d_in[8];
  const float* WC_w  = (const float*)d_in[9];
  const float* WC_b  = (const float*)d_in[10];
  float* out = (float*)d_out;

  char* p = (char*)d_ws;
  auto alloc = [&](size_t bytes) {
    char* r = p;
    p += (bytes + 255) & ~(size_t)255;
    return r;
  };
  u16* hsb   = (u16*)alloc((size_t)Mz * Dz * 2);        // hs bf16; reused as attn out
  u16* wcat  = (u16*)alloc((size_t)2048 * Dz * 2);      // [WQ*c; WKA; WVA] rows
  u16* wkbb  = (u16*)alloc((size_t)Dz * Rz * 2);
  u16* wvbb  = (u16*)alloc((size_t)Dz * Rz * 2);
  u16* wcb   = (u16*)alloc((size_t)Dz * Dz * 2);        // c_proj_w transposed
  float* bcat = (float*)alloc((size_t)2048 * 4);        // [WQ_b*c, zeros]
  u16* QA    = (u16*)alloc((size_t)Mz * 2048 * 2);      // cols 0-1023: Q', 1024-2047: KA|VA
  u16* Kb    = (u16*)alloc((size_t)Mz * Dz * 2);
  u16* Vtg   = (u16*)alloc((size_t)Mz * Dz * 2);        // [bh][64][2048]
  u16* AOb   = hsb;                                     // attn out overwrites hs bf16

  const float SC = 0.18033688f;  // log2(e)/8, folded into Q projection

  // converts (weight concat: rows 0-1023=WQ*SC, 1024-1535=WKA, 1536-2047=WVA)
  convert_bf16<<<(Mz * Dz) / 8 / 256, 256, 0, stream>>>(hs, hsb, Mz * Dz, 1.0f);
  convert_bf16<<<(Dz * Dz) / 8 / 256, 256, 0, stream>>>(WQ_w, wcat, Dz * Dz, SC);
  convert_bf16<<<(Rz * Dz) / 8 / 256, 256, 0, stream>>>(WKA_w, wcat + (size_t)Dz * Dz,
                                                        Rz * Dz, 1.0f);
  convert_bf16<<<(Rz * Dz) / 8 / 256, 256, 0, stream>>>(WVA_w, wcat + (size_t)1536 * Dz,
                                                        Rz * Dz, 1.0f);
  convert_bf16<<<(Dz * Rz) / 8 / 256, 256, 0, stream>>>(WKB_w, wkbb, Dz * Rz, 1.0f);
  convert_bf16<<<(Dz * Rz) / 8 / 256, 256, 0, stream>>>(WVB_w, wvbb, Dz * Rz, 1.0f);
  transpose_convert<<<dim3(Dz / 32, Dz / 32), dim3(32, 8), 0, stream>>>(WC_w, wcb, Dz, Dz);
  make_biascat<<<8, 256, 0, stream>>>(WQ_b, bcat);

  // fused Q|KA|VA projection: QA[8192][2048] = hsb * wcat^T + bcat
  gemm256<256><<<dim3(2048 / 256, Mz / 256, 1), 512, 0, stream>>>(
      hsb, wcat, bcat, QA, 0, hsb, wcat, bcat, QA, 0, 2048, Dz, Dz);

  // z-batched K and V GEMMs (K: bf16 row-major; V: written transposed)
  gemm256<256><<<dim3(Dz / 256, Mz / 256, 2), 512, 0, stream>>>(
      QA + Dz, wkbb, WKB_b, Kb, 0,
      QA + 1536, wvbb, WVB_b, Vtg, 2, Dz, Rz, 2048);

  // attention (Q from QA cols 0-1023, lda 2048); paired q-tiles, grid.x = 8
  attn_kernel<<<dim3(Sz / 256, Bz * Hz), 256, 0, stream>>>(QA, Kb, Vtg, AOb);

  // output projection -> f32 (128x256 tile: grid 4x64 = 256 blocks = 1/CU)
  gemm256<128><<<dim3(Dz / 256, Mz / 128, 1), 512, 0, stream>>>(
      AOb, wcb, WC_b, out, 1, AOb, wcb, WC_b, out, 1, Dz, Dz, Dz);
}